// Round 2
// 370.489 us; speedup vs baseline: 1.0460x; 1.0460x over previous
//
#include <hip/hip_runtime.h>
#include <hip/hip_bf16.h>
#include <stdint.h>

#define D_MODEL 1024
#define S_LEN   2048
#define BATCH   4
#define NH      8
#define DK      128

typedef __attribute__((ext_vector_type(8))) __bf16 bf16x8;
typedef __attribute__((ext_vector_type(4))) float  f32x4;

__device__ __forceinline__ f32x4 mfma16(bf16x8 a, bf16x8 b, f32x4 c) {
  return __builtin_amdgcn_mfma_f32_16x16x32_bf16(a, b, c, 0, 0, 0);
}

// async global->LDS, 16B per lane; lds base is wave-uniform, HW writes
// ldsbase + lane*16 (guide §5, m97/m104).
__device__ __forceinline__ void gld_lds16(const void* g, void* l) {
  __builtin_amdgcn_global_load_lds(
      (const __attribute__((address_space(1))) void*)g,
      (__attribute__((address_space(3))) void*)l, 16, 0, 0);
}

#define ATTN_SCALE 0.08838834764831845f  // 1/sqrt(128), folded into Wq/bq

// ---------------------------------------------------------------------------
// Kernel 0a: fp32 -> bf16 convert of the three activation tensors.
// ---------------------------------------------------------------------------
__global__ __launch_bounds__(256) void cvt_kernel(
    const float* __restrict__ x0, const float* __restrict__ x1,
    const float* __restrict__ x2, __hip_bfloat16* __restrict__ out) {
  const size_t N = (size_t)BATCH * S_LEN * D_MODEL;  // 8M elems
  const int w = blockIdx.y;
  const float* src = (w == 0) ? x0 : (w == 1) ? x1 : x2;
  __hip_bfloat16* dst = out + (size_t)w * N;
  const size_t i = ((size_t)blockIdx.x * 256 + threadIdx.x) * 4;
  const float4 v = *(const float4*)(src + i);
  *(__hip_bfloat162*)(dst + i)     = __float22bfloat162_rn(make_float2(v.x, v.y));
  *(__hip_bfloat162*)(dst + i + 2) = __float22bfloat162_rn(make_float2(v.z, v.w));
}

// ---------------------------------------------------------------------------
// Kernel 0b: transpose+convert weights W[k][n] fp32 -> Wt[n][k] bf16.
// Wq pre-scaled by 1/sqrt(dk).
// ---------------------------------------------------------------------------
__global__ void wtrans_kernel(const float* __restrict__ Wq,
                              const float* __restrict__ Wk,
                              const float* __restrict__ Wv,
                              __hip_bfloat16* __restrict__ Wt) {
  __shared__ __hip_bfloat16 tile[32][33];
  const int w = blockIdx.z;
  const float* src = (w == 0) ? Wq : (w == 1) ? Wk : Wv;
  const float sc = (w == 0) ? ATTN_SCALE : 1.0f;
  __hip_bfloat16* dst = Wt + (size_t)w * D_MODEL * D_MODEL;
  const int tx = threadIdx.x, ty = threadIdx.y;
  int x = blockIdx.x * 32 + tx;
  int y = blockIdx.y * 32 + ty;
  for (int i = 0; i < 32; i += 8)
    tile[ty + i][tx] = __float2bfloat16(src[(size_t)(y + i) * D_MODEL + x] * sc);
  __syncthreads();
  x = blockIdx.y * 32 + tx;
  y = blockIdx.x * 32 + ty;
  for (int i = 0; i < 32; i += 8)
    dst[(size_t)(y + i) * D_MODEL + x] = tile[tx][ty + i];
}

// ---------------------------------------------------------------------------
// Kernel 1: QKV projection GEMM (m97 structure, bf16 staged A and B).
// XCD-grouped block order. Q,K -> [B,H,S,dk]; V -> [B,H,dk,S].
// ---------------------------------------------------------------------------
__global__ __launch_bounds__(256) void qkv_gemm_kernel(
    const __hip_bfloat16* __restrict__ Xbf,
    const float* __restrict__ bq, const float* __restrict__ bk,
    const float* __restrict__ bv,
    const __hip_bfloat16* __restrict__ Wt,
    __hip_bfloat16* __restrict__ Qo, __hip_bfloat16* __restrict__ Ko,
    __hip_bfloat16* __restrict__ Vo) {
  const int flat = blockIdx.x;          // 0..1535
  const int xcd  = flat & 7;
  const int idx  = flat >> 3;           // 0..191
  const int n_t  = idx & 7;
  const int mg   = idx >> 3;            // 0..23
  const int pair = xcd * 24 + mg;       // 0..191 = 64 m-tiles x 3 slices
  const int which = pair >> 6;
  const int m_t   = pair & 63;

  const size_t N = (size_t)BATCH * S_LEN * D_MODEL;
  const __hip_bfloat16* X = Xbf + (size_t)which * N;
  const __hip_bfloat16* W = Wt + (size_t)which * D_MODEL * D_MODEL;
  const float* bias = (which == 0) ? bq : (which == 1) ? bk : bv;
  const float bscale = (which == 0) ? ATTN_SCALE : 1.0f;

  __shared__ __align__(16) __hip_bfloat16 Asm[128 * 32];
  __shared__ __align__(16) __hip_bfloat16 Bsm[128 * 32];

  const int tid  = threadIdx.x;
  const int lane = tid & 63;
  const int wv   = tid >> 6;
  const int lo16 = lane & 15;
  const int hi4  = lane >> 4;
  const int m0 = m_t * 128;
  const int n0 = n_t * 128;
  const int wm = (wv >> 1) * 64;
  const int wn = (wv & 1) * 64;

  f32x4 acc[4][4];
  const f32x4 z4 = {0.f, 0.f, 0.f, 0.f};
  for (int i = 0; i < 4; ++i)
    for (int j = 0; j < 4; ++j) acc[i][j] = z4;

  for (int k0 = 0; k0 < D_MODEL; k0 += 32) {
    __syncthreads();
    for (int it = 0; it < 2; ++it) {
      const int cbase = it * 256 + wv * 64;
      const int c = cbase + lane;
      gld_lds16(X + (size_t)(m0 + (c >> 2)) * D_MODEL + k0 + (c & 3) * 8,
                &Asm[cbase * 8]);
      gld_lds16(W + (size_t)(n0 + (c >> 2)) * D_MODEL + k0 + (c & 3) * 8,
                &Bsm[cbase * 8]);
    }
    __syncthreads();

    bf16x8 af[4], bfr[4];
    for (int i = 0; i < 4; ++i)
      af[i] = *(const bf16x8*)&Asm[(wm + 16 * i + lo16) * 32 + hi4 * 8];
    for (int j = 0; j < 4; ++j)
      bfr[j] = *(const bf16x8*)&Bsm[(wn + 16 * j + lo16) * 32 + hi4 * 8];
    for (int i = 0; i < 4; ++i)
      for (int j = 0; j < 4; ++j)
        acc[i][j] = mfma16(af[i], bfr[j], acc[i][j]);
  }

  const int b = m0 >> 11;
  for (int j = 0; j < 4; ++j) {
    const int n = n0 + wn + j * 16 + lo16;
    const float bval = bias[n] * bscale;
    const int h = n >> 7;
    const int d = n & 127;
    for (int i = 0; i < 4; ++i) {
      for (int r = 0; r < 4; ++r) {
        const int m = m0 + wm + 16 * i + hi4 * 4 + r;
        const int s = m & (S_LEN - 1);
        const __hip_bfloat16 ob = __float2bfloat16(acc[i][j][r] + bval);
        if (which == 0)
          Qo[((size_t)(b * NH + h) * S_LEN + s) * DK + d] = ob;
        else if (which == 1)
          Ko[((size_t)(b * NH + h) * S_LEN + s) * DK + d] = ob;
        else
          Vo[((size_t)(b * NH + h) * DK + d) * S_LEN + s] = ob;
      }
    }
  }
}

// ---------------------------------------------------------------------------
// Kernel 2: causal flash attention, SPLIT-KV + balanced-triple schedule.
//
// Theory: grid (16,NH,B) + 2-blocks/CU LDS made co-resident pairs
// SAME-TILE -> worst CU ran 128 kv-steps vs 68 avg; kernel was
// latency-bound at 10% MfmaUtil. This version:
//  - tiles 8..15 split into 2 equal kv-chunks. Constant-max softmax
//    (p = exp(s-8), no running max) makes partials purely additive:
//    chunk blocks emit unnormalized fp32 partial O + partial row-sum;
//    ln_kernel does the (p0+p1)/(l0+l1) combine for free.
//  - 768 blocks = 256 CUs x 3 slots, ALL resident (LDS cut to 43KB via
//    2 staging buffers). Block table groups work into exact 68-step
//    triples per CU slot-column: (32,32,4)(30,30,8)(28,28,12)(26,26,16)
//    (24,24,20)(32,18,18)(28,20,20)(24,22,22).
//  - bid%8 == h: all blocks of a (b,h) pinned to one XCD -> its 4MB of
//    K/V lives in that XCD's L2.
//  - staging addresses hoisted to per-thread base pointers.
//  - stage(st+1) issued right after the barrier; vmcnt(0) for tile st
//    was issued one full compute phase earlier -> HBM latency hidden.
// ---------------------------------------------------------------------------
__device__ const uint32_t ATTN_TBL[24] = {
  // pack = tile | chunk<<4 | nchunks<<5 ; rows j=0..7, cols r=0..2
  79, 95, 32,   // t15h0(32) t15h1(32) t0(4)
  78, 94, 33,   // t14h0(30) t14h1(30) t1(8)
  77, 93, 34,   // t13h0(28) t13h1(28) t2(12)
  76, 92, 35,   // t12h0(26) t12h1(26) t3(16)
  75, 91, 36,   // t11h0(24) t11h1(24) t4(20)
  39, 72, 88,   // t7(32)    t8h0(18)  t8h1(18)
  38, 73, 89,   // t6(28)    t9h0(20)  t9h1(20)
  37, 74, 90    // t5(24)    t10h0(22) t10h1(22)
};

__global__ __launch_bounds__(256) void attn_kernel(
    const __hip_bfloat16* __restrict__ Qw, const __hip_bfloat16* __restrict__ Kw,
    const __hip_bfloat16* __restrict__ Vtw, __hip_bfloat16* __restrict__ Og,
    float* __restrict__ partO, float* __restrict__ lsumP) {
  const int bid = blockIdx.x;       // 0..767
  const int q8  = bid & 255;        // CU slot-column; q8%8 = bh%8 = h (XCD pin)
  const int rr  = bid >> 8;         // dispatch round 0..2
  const int bh  = q8 & 31;
  const int jrow = q8 >> 5;         // 0..7
  const int h   = bh & 7;
  const int b   = bh >> 3;
  const uint32_t wi = ATTN_TBL[jrow * 3 + rr];
  const int  t     = wi & 15;
  const int  chnk  = (wi >> 4) & 1;
  const bool split = (wi >> 5) == 2;
  const int  half  = 2 * t + 2;
  const int  st0   = (split && chnk == 1) ? half : 0;
  const int  stN   = (split && chnk == 0) ? half : (4 * t + 4);

  const int tid  = threadIdx.x;
  const int lane = tid & 63;
  const int wv   = tid >> 6;
  const int lo16 = lane & 15;
  const int hi4  = lane >> 4;

  const int qrow0 = t * 128 + wv * 32;   // this wave's 32 q rows (global)
  const int ns_w  = 4 * t + wv + 1;      // causal kv32 limit for this wave

  const size_t bhp = (size_t)(b * NH + h);
  const __hip_bfloat16* Qp = Qw + bhp * S_LEN * DK;
  const __hip_bfloat16* Kp = Kw + bhp * S_LEN * DK;
  const __hip_bfloat16* Vp = Vtw + bhp * DK * S_LEN;  // [dk][S]

  __shared__ __align__(16) __hip_bfloat16 Ksm[2][32 * 128];  // [dchunk16][kv32]
  __shared__ __align__(16) __hip_bfloat16 Vsm[2][128 * 32];  // [kvchunk4][d128]
  __shared__ __align__(16) __hip_bfloat16 Psm[4][32 * 40];   // per-wave P

  // Q fragments: A[m=lo16][k=hi4*8+j]; 2 m-groups x 4 k-steps cover 32q x 128d
  bf16x8 qf[2][4];
  for (int m = 0; m < 2; ++m)
    for (int kk = 0; kk < 4; ++kk)
      qf[m][kk] = *(const bf16x8*)&Qp[(size_t)(qrow0 + m * 16 + lo16) * DK +
                                      kk * 32 + hi4 * 8];

  f32x4 oacc[2][8];
  const f32x4 z4 = {0.f, 0.f, 0.f, 0.f};
  for (int m = 0; m < 2; ++m)
    for (int j = 0; j < 8; ++j) oacc[m][j] = z4;
  float lsum[2][4];
  for (int m = 0; m < 2; ++m)
    for (int i = 0; i < 4; ++i) lsum[m][i] = 0.f;

  // hoisted per-thread staging base addresses (chunk c = it*256 + tid)
  const __hip_bfloat16* kbase[2];
  const __hip_bfloat16* vbase[2];
#pragma unroll
  for (int it = 0; it < 2; ++it) {
    const int c = it * 256 + tid;
    kbase[it] = Kp + (size_t)(c & 31) * DK + (c >> 5) * 8;
    vbase[it] = Vp + (size_t)(c & 127) * S_LEN + (c >> 7) * 8;
  }
  // stage kv32 tile `st` into buffer `buf`: exactly 4 gld_lds16 per thread
  auto stage = [&](int st, int buf) {
#pragma unroll
    for (int it = 0; it < 2; ++it) {
      const int cb = (it * 256 + wv * 64) * 8;
      gld_lds16(kbase[it] + (st << 12), &Ksm[buf][cb]);  // st*32*DK elems
      gld_lds16(vbase[it] + (st << 5),  &Vsm[buf][cb]);  // st*32 elems
    }
  };

  stage(st0, 0);

  int bsel = 0;
  for (int st = st0; st < stN; ++st) {
    // tile st's 4 loads were issued one full compute phase ago
    asm volatile("s_waitcnt vmcnt(0)" ::: "memory");
    __builtin_amdgcn_s_barrier();
    asm volatile("" ::: "memory");  // no LDS reads hoist above the barrier
    // prefetch next tile into the buffer everyone finished reading at st-1
    if (st + 1 < stN) stage(st + 1, bsel ^ 1);

    if (st < ns_w) {
      const __hip_bfloat16* Kb = Ksm[bsel];
      const __hip_bfloat16* Vb = Vsm[bsel];

      // QK^T: S[32q][32kv] as 2m x 2kn 16x16 tiles
      bf16x8 kf[2][4];
      for (int kn = 0; kn < 2; ++kn)
        for (int kk = 0; kk < 4; ++kk)
          kf[kn][kk] = *(const bf16x8*)&Kb[((kk * 4 + hi4) * 32 + kn * 16 + lo16) * 8];
      f32x4 sc[2][2];
      for (int m = 0; m < 2; ++m)
        for (int kn = 0; kn < 2; ++kn) {
          f32x4 s4 = z4;
          for (int kk = 0; kk < 4; ++kk)
            s4 = mfma16(qf[m][kk], kf[kn][kk], s4);
          sc[m][kn] = s4;
        }

      // constant-max softmax; C/D row = hi4*4+reg, col = lo16
      const int kv0 = st << 5;
      const bool do_mask = (st == ns_w - 1);  // only the diagonal step masks
      for (int m = 0; m < 2; ++m) {
        for (int i = 0; i < 4; ++i) {
          const int qg = qrow0 + m * 16 + hi4 * 4 + i;
          float s0 = sc[m][0][i];
          float s1 = sc[m][1][i];
          if (do_mask) {
            if (kv0 + lo16 > qg)      s0 = -1.0e30f;
            if (kv0 + 16 + lo16 > qg) s1 = -1.0e30f;
          }
          const float p0 = __expf(s0 - 8.f);
          const float p1 = __expf(s1 - 8.f);
          lsum[m][i] += p0 + p1;
          const int prw = m * 16 + hi4 * 4 + i;
          Psm[wv][prw * 40 + lo16]      = __float2bfloat16(p0);
          Psm[wv][prw * 40 + 16 + lo16] = __float2bfloat16(p1);
        }
      }
      // wave-local LDS round-trip: order + drain without any barrier
      asm volatile("s_waitcnt lgkmcnt(0)" ::: "memory");

      // PV: A = P[q16][kv32] per m-group, B = Vt[d][kv]; V frags shared by m
      bf16x8 pf[2];
      for (int m = 0; m < 2; ++m)
        pf[m] = *(const bf16x8*)&Psm[wv][(m * 16 + lo16) * 40 + hi4 * 8];
      for (int j = 0; j < 8; ++j) {
        const bf16x8 vf = *(const bf16x8*)&Vb[(hi4 * 128 + j * 16 + lo16) * 8];
        oacc[0][j] = mfma16(pf[0], vf, oacc[0][j]);
        oacc[1][j] = mfma16(pf[1], vf, oacc[1][j]);
      }
    }
    bsel ^= 1;
  }

  // epilogue: row-sum reduce over 16-lane groups, then either normalized
  // bf16 O (whole-tile blocks) or fp32 partials (split-tile blocks).
  for (int m = 0; m < 2; ++m) {
    for (int i = 0; i < 4; ++i) {
      float l = lsum[m][i];
      l += __shfl_xor(l, 1);
      l += __shfl_xor(l, 2);
      l += __shfl_xor(l, 4);
      l += __shfl_xor(l, 8);
      const int row = wv * 32 + m * 16 + hi4 * 4 + i;   // row within tile
      if (!split) {
        const float inv = 1.0f / l;
        const int qg = t * 128 + row;
        __hip_bfloat16* orow = Og + ((size_t)b * S_LEN + qg) * D_MODEL + h * DK;
        for (int j = 0; j < 8; ++j)
          orow[j * 16 + lo16] = __float2bfloat16(oacc[m][j][i] * inv);
      } else {
        const int pidx = bh * 8 + (t - 8);               // 0..255
        float* prow = partO +
            (((size_t)chnk * 256 + pidx) * 128 + row) * 128;
        for (int j = 0; j < 8; ++j)
          prow[j * 16 + lo16] = oacc[m][j][i];
        if (lo16 == 0)
          lsumP[(chnk * 256 + pidx) * 128 + row] = l;
      }
    }
  }
}

// ---------------------------------------------------------------------------
// Kernel 3: residual + LayerNorm, one block per row. Rows in tiles 8..15
// additionally combine the two split-KV partials: (p0+p1)/(l0+l1).
// ---------------------------------------------------------------------------
__global__ __launch_bounds__(256) void ln_kernel(
    const __hip_bfloat16* __restrict__ Og, const float* __restrict__ partO,
    const float* __restrict__ lsumP, const float* __restrict__ resid_in,
    const float* __restrict__ gamma, const float* __restrict__ beta,
    float* __restrict__ out) {
  const int row  = blockIdx.x;          // 0..8191
  const int b    = row >> 11;
  const int srow = row & (S_LEN - 1);
  const int tile = srow >> 7;
  const int tid  = threadIdx.x;
  const int base = tid * 4;
  const float4 q4 = *(const float4*)(resid_in + (size_t)row * D_MODEL + base);
  float v[4];
  if (tile < 8) {
    const __hip_bfloat16* orow = Og + (size_t)row * D_MODEL;
    const ushort4 o4 = *(const ushort4*)(orow + base);
    v[0] = __bfloat162float(*(const __hip_bfloat16*)&o4.x) + q4.x;
    v[1] = __bfloat162float(*(const __hip_bfloat16*)&o4.y) + q4.y;
    v[2] = __bfloat162float(*(const __hip_bfloat16*)&o4.z) + q4.z;
    v[3] = __bfloat162float(*(const __hip_bfloat16*)&o4.w) + q4.w;
  } else {
    const int h    = base >> 7;
    const int rin  = srow & 127;
    const int pidx = (b * 8 + h) * 8 + (tile - 8);
    const size_t off = ((size_t)pidx * 128 + rin) * 128 + (base & 127);
    const float4 p0 = *(const float4*)(partO + off);
    const float4 p1 = *(const float4*)(partO + (size_t)256 * 128 * 128 + off);
    const float l = lsumP[pidx * 128 + rin] +
                    lsumP[256 * 128 + pidx * 128 + rin];
    const float inv = 1.0f / l;
    v[0] = (p0.x + p1.x) * inv + q4.x;
    v[1] = (p0.y + p1.y) * inv + q4.y;
    v[2] = (p0.z + p1.z) * inv + q4.z;
    v[3] = (p0.w + p1.w) * inv + q4.w;
  }
  float s = v[0] + v[1] + v[2] + v[3];
  float ss = v[0] * v[0] + v[1] * v[1] + v[2] * v[2] + v[3] * v[3];
  for (int m = 1; m < 64; m <<= 1) { s += __shfl_xor(s, m); ss += __shfl_xor(ss, m); }
  __shared__ float red[8];
  const int wv = tid >> 6, lane = tid & 63;
  if (lane == 0) { red[wv] = s; red[4 + wv] = ss; }
  __syncthreads();
  s  = red[0] + red[1] + red[2] + red[3];
  ss = red[4] + red[5] + red[6] + red[7];
  const float mu  = s * (1.0f / D_MODEL);
  const float var = ss * (1.0f / D_MODEL) - mu * mu;
  const float rstd = rsqrtf(var + 1e-6f);
  const float4 g4 = *(const float4*)(gamma + base);
  const float4 b4 = *(const float4*)(beta + base);
  float4 o;
  o.x = (v[0] - mu) * rstd * g4.x + b4.x;
  o.y = (v[1] - mu) * rstd * g4.y + b4.y;
  o.z = (v[2] - mu) * rstd * g4.z + b4.z;
  o.w = (v[3] - mu) * rstd * g4.w + b4.w;
  *(float4*)(out + (size_t)row * D_MODEL + base) = o;
}

// ---------------------------------------------------------------------------
extern "C" void kernel_launch(void* const* d_in, const int* in_sizes, int n_in,
                              void* d_out, int out_size, void* d_ws, size_t ws_size,
                              hipStream_t stream) {
  const float* queries = (const float*)d_in[0];
  const float* keys    = (const float*)d_in[1];
  const float* values  = (const float*)d_in[2];
  const float* Wq = (const float*)d_in[3];
  const float* bq = (const float*)d_in[4];
  const float* Wk = (const float*)d_in[5];
  const float* bk = (const float*)d_in[6];
  const float* Wv = (const float*)d_in[7];
  const float* bv = (const float*)d_in[8];
  const float* gamma = (const float*)d_in[9];
  const float* beta  = (const float*)d_in[10];

  char* ws = (char*)d_ws;
  const size_t N = (size_t)BATCH * S_LEN * D_MODEL;                 // 8M
  const size_t WT_BYTES  = (size_t)3 * D_MODEL * D_MODEL * 2;      // 6 MB
  const size_t XBF_BYTES = (size_t)3 * N * 2;                      // 48 MB
  const size_t QKV_BYTES = (size_t)BATCH * NH * S_LEN * DK * 2;    // 16 MB
  const size_t OG_BYTES  = (size_t)BATCH * S_LEN * D_MODEL * 2;    // 16 MB
  __hip_bfloat16* Wt  = (__hip_bfloat16*)ws;
  __hip_bfloat16* Xbf = (__hip_bfloat16*)(ws + WT_BYTES);
  // After qkv_gemm, the Xbf (48MB) and Wt (6MB) regions are dead:
  //   Og   bf16 16MB  @ XBF+0      (rows of tiles 0..7 only)
  //   partO f32 32MB  @ XBF+16MB   ([2 splits][256 pidx][128 row][128 d])
  //   lsumP f32 256KB @ ws+0       ([2 splits][256 pidx][128 row])
  __hip_bfloat16* Ogs = (__hip_bfloat16*)(ws + WT_BYTES);
  float* partO = (float*)(ws + WT_BYTES + OG_BYTES);
  float* lsumP = (float*)ws;
  __hip_bfloat16* Qws = (__hip_bfloat16*)(ws + WT_BYTES + XBF_BYTES);
  __hip_bfloat16* Kws = (__hip_bfloat16*)(ws + WT_BYTES + XBF_BYTES + QKV_BYTES);
  __hip_bfloat16* Vws = (__hip_bfloat16*)(ws + WT_BYTES + XBF_BYTES + 2 * QKV_BYTES);

  cvt_kernel<<<dim3((unsigned)(N / 1024), 3), 256, 0, stream>>>(queries, keys, values, Xbf);
  wtrans_kernel<<<dim3(32, 32, 3), dim3(32, 8), 0, stream>>>(Wq, Wk, Wv, Wt);
  qkv_gemm_kernel<<<dim3(1536), 256, 0, stream>>>(
      Xbf, bq, bk, bv, Wt, Qws, Kws, Vws);
  attn_kernel<<<dim3(768), 256, 0, stream>>>(Qws, Kws, Vws, Ogs, partO, lsumP);
  ln_kernel<<<dim3(BATCH * S_LEN), 256, 0, stream>>>(Ogs, partO, lsumP, queries,
                                                     gamma, beta, (float*)d_out);
}

// Round 3
// 347.533 us; speedup vs baseline: 1.1151x; 1.0661x over previous
//
#include <hip/hip_runtime.h>
#include <hip/hip_bf16.h>
#include <stdint.h>

#define D_MODEL 1024
#define S_LEN   2048
#define BATCH   4
#define NH      8
#define DK      128

typedef __attribute__((ext_vector_type(8))) __bf16 bf16x8;
typedef __attribute__((ext_vector_type(4))) float  f32x4;

__device__ __forceinline__ f32x4 mfma16(bf16x8 a, bf16x8 b, f32x4 c) {
  return __builtin_amdgcn_mfma_f32_16x16x32_bf16(a, b, c, 0, 0, 0);
}

// async global->LDS, 16B per lane; lds base is wave-uniform, HW writes
// ldsbase + lane*16 (guide §5, m97/m104).
__device__ __forceinline__ void gld_lds16(const void* g, void* l) {
  __builtin_amdgcn_global_load_lds(
      (const __attribute__((address_space(1))) void*)g,
      (__attribute__((address_space(3))) void*)l, 16, 0, 0);
}

#define ATTN_SCALE 0.08838834764831845f  // 1/sqrt(128), folded into Wq/bq

// ---------------------------------------------------------------------------
// Kernel 0a: fp32 -> bf16 convert of the three activation tensors.
// ---------------------------------------------------------------------------
__global__ __launch_bounds__(256) void cvt_kernel(
    const float* __restrict__ x0, const float* __restrict__ x1,
    const float* __restrict__ x2, __hip_bfloat16* __restrict__ out) {
  const size_t N = (size_t)BATCH * S_LEN * D_MODEL;  // 8M elems
  const int w = blockIdx.y;
  const float* src = (w == 0) ? x0 : (w == 1) ? x1 : x2;
  __hip_bfloat16* dst = out + (size_t)w * N;
  const size_t i = ((size_t)blockIdx.x * 256 + threadIdx.x) * 4;
  const float4 v = *(const float4*)(src + i);
  *(__hip_bfloat162*)(dst + i)     = __float22bfloat162_rn(make_float2(v.x, v.y));
  *(__hip_bfloat162*)(dst + i + 2) = __float22bfloat162_rn(make_float2(v.z, v.w));
}

// ---------------------------------------------------------------------------
// Kernel 0b: transpose+convert weights W[k][n] fp32 -> Wt[n][k] bf16.
// Wq pre-scaled by 1/sqrt(dk).
// ---------------------------------------------------------------------------
__global__ void wtrans_kernel(const float* __restrict__ Wq,
                              const float* __restrict__ Wk,
                              const float* __restrict__ Wv,
                              __hip_bfloat16* __restrict__ Wt) {
  __shared__ __hip_bfloat16 tile[32][33];
  const int w = blockIdx.z;
  const float* src = (w == 0) ? Wq : (w == 1) ? Wk : Wv;
  const float sc = (w == 0) ? ATTN_SCALE : 1.0f;
  __hip_bfloat16* dst = Wt + (size_t)w * D_MODEL * D_MODEL;
  const int tx = threadIdx.x, ty = threadIdx.y;
  int x = blockIdx.x * 32 + tx;
  int y = blockIdx.y * 32 + ty;
  for (int i = 0; i < 32; i += 8)
    tile[ty + i][tx] = __float2bfloat16(src[(size_t)(y + i) * D_MODEL + x] * sc);
  __syncthreads();
  x = blockIdx.y * 32 + tx;
  y = blockIdx.x * 32 + ty;
  for (int i = 0; i < 32; i += 8)
    dst[(size_t)(y + i) * D_MODEL + x] = tile[tx][ty + i];
}

// ---------------------------------------------------------------------------
// Kernel 1: QKV projection GEMM (m97 structure, bf16 staged A and B).
// XCD-grouped block order. Q -> [B,H,S,dk] natural.
// K -> TILE-BLOCKED LDS-image layout: Kb[bh][tile64][dchunk16][kv32][8e]
// V -> TILE-BLOCKED LDS-image layout: Vb[bh][tile64][kvchunk4][d128][8e]
// so each attn kv32-tile is one contiguous 8KB block (coalesced staging).
// ---------------------------------------------------------------------------
__global__ __launch_bounds__(256) void qkv_gemm_kernel(
    const __hip_bfloat16* __restrict__ Xbf,
    const float* __restrict__ bq, const float* __restrict__ bk,
    const float* __restrict__ bv,
    const __hip_bfloat16* __restrict__ Wt,
    __hip_bfloat16* __restrict__ Qo, __hip_bfloat16* __restrict__ Ko,
    __hip_bfloat16* __restrict__ Vo) {
  const int flat = blockIdx.x;          // 0..1535
  const int xcd  = flat & 7;
  const int idx  = flat >> 3;           // 0..191
  const int n_t  = idx & 7;
  const int mg   = idx >> 3;            // 0..23
  const int pair = xcd * 24 + mg;       // 0..191 = 64 m-tiles x 3 slices
  const int which = pair >> 6;
  const int m_t   = pair & 63;

  const size_t N = (size_t)BATCH * S_LEN * D_MODEL;
  const __hip_bfloat16* X = Xbf + (size_t)which * N;
  const __hip_bfloat16* W = Wt + (size_t)which * D_MODEL * D_MODEL;
  const float* bias = (which == 0) ? bq : (which == 1) ? bk : bv;
  const float bscale = (which == 0) ? ATTN_SCALE : 1.0f;

  __shared__ __align__(16) __hip_bfloat16 Asm[128 * 32];
  __shared__ __align__(16) __hip_bfloat16 Bsm[128 * 32];

  const int tid  = threadIdx.x;
  const int lane = tid & 63;
  const int wv   = tid >> 6;
  const int lo16 = lane & 15;
  const int hi4  = lane >> 4;
  const int m0 = m_t * 128;
  const int n0 = n_t * 128;
  const int wm = (wv >> 1) * 64;
  const int wn = (wv & 1) * 64;

  f32x4 acc[4][4];
  const f32x4 z4 = {0.f, 0.f, 0.f, 0.f};
  for (int i = 0; i < 4; ++i)
    for (int j = 0; j < 4; ++j) acc[i][j] = z4;

  for (int k0 = 0; k0 < D_MODEL; k0 += 32) {
    __syncthreads();
    for (int it = 0; it < 2; ++it) {
      const int cbase = it * 256 + wv * 64;
      const int c = cbase + lane;
      gld_lds16(X + (size_t)(m0 + (c >> 2)) * D_MODEL + k0 + (c & 3) * 8,
                &Asm[cbase * 8]);
      gld_lds16(W + (size_t)(n0 + (c >> 2)) * D_MODEL + k0 + (c & 3) * 8,
                &Bsm[cbase * 8]);
    }
    __syncthreads();

    bf16x8 af[4], bfr[4];
    for (int i = 0; i < 4; ++i)
      af[i] = *(const bf16x8*)&Asm[(wm + 16 * i + lo16) * 32 + hi4 * 8];
    for (int j = 0; j < 4; ++j)
      bfr[j] = *(const bf16x8*)&Bsm[(wn + 16 * j + lo16) * 32 + hi4 * 8];
    for (int i = 0; i < 4; ++i)
      for (int j = 0; j < 4; ++j)
        acc[i][j] = mfma16(af[i], bfr[j], acc[i][j]);
  }

  const int b = m0 >> 11;
  for (int j = 0; j < 4; ++j) {
    const int n = n0 + wn + j * 16 + lo16;
    const float bval = bias[n] * bscale;
    const int h = n >> 7;
    const int d = n & 127;
    for (int i = 0; i < 4; ++i) {
      for (int r = 0; r < 4; ++r) {
        const int m = m0 + wm + 16 * i + hi4 * 4 + r;
        const int s = m & (S_LEN - 1);
        const __hip_bfloat16 ob = __float2bfloat16(acc[i][j][r] + bval);
        const size_t bh = (size_t)(b * NH + h);
        if (which == 0) {
          Qo[(bh * S_LEN + s) * DK + d] = ob;
        } else if (which == 1) {
          // Kb[bh][tile][d>>3][s&31][d&7]
          Ko[(bh * 64 + (s >> 5)) * 4096 + (d >> 3) * 256 + (s & 31) * 8 +
             (d & 7)] = ob;
        } else {
          // Vb[bh][tile][(s&31)>>3][d][s&7]
          Vo[(bh * 64 + (s >> 5)) * 4096 + ((s & 31) >> 3) * 1024 + d * 8 +
             (s & 7)] = ob;
        }
      }
    }
  }
}

// ---------------------------------------------------------------------------
// Kernel 2: causal flash attention, SPLIT-KV + balanced-triple schedule +
// COALESCED tile-blocked staging.
//
// R2 post-mortem: per-step cost was ~3800 cyc, dominated by vmcnt(0) on
// staging loads that were scatter-pattern (V: 64 lanes at 4096B stride).
// K/V are now stored tile-blocked (8KB contiguous per kv32 tile, exactly
// the LDS image), so stage() = 4 fully-coalesced 16B/lane block reads.
//  - tiles 8..15 split into 2 kv-chunks (additive partials, constant-max
//    softmax; combine folded into ln_kernel).
//  - 768 blocks = 256 CUs x 3 slots, all resident (43KB LDS, 2 buffers).
//    ATTN_TBL packs each CU slot-column into a 68-step triple.
//  - bid%8 == h pins each (b,h)'s K/V to one XCD's L2.
//  - prefetch st+1 issued right after barrier; vmcnt(0) lands one full
//    compute phase later.
// ---------------------------------------------------------------------------
__device__ const uint32_t ATTN_TBL[24] = {
  // pack = tile | chunk<<4 | nchunks<<5 ; rows j=0..7, cols r=0..2
  79, 95, 32,   // t15h0(32) t15h1(32) t0(4)
  78, 94, 33,   // t14h0(30) t14h1(30) t1(8)
  77, 93, 34,   // t13h0(28) t13h1(28) t2(12)
  76, 92, 35,   // t12h0(26) t12h1(26) t3(16)
  75, 91, 36,   // t11h0(24) t11h1(24) t4(20)
  39, 72, 88,   // t7(32)    t8h0(18)  t8h1(18)
  38, 73, 89,   // t6(28)    t9h0(20)  t9h1(20)
  37, 74, 90    // t5(24)    t10h0(22) t10h1(22)
};

__global__ __launch_bounds__(256) void attn_kernel(
    const __hip_bfloat16* __restrict__ Qw, const __hip_bfloat16* __restrict__ Kw,
    const __hip_bfloat16* __restrict__ Vtw, __hip_bfloat16* __restrict__ Og,
    float* __restrict__ partO, float* __restrict__ lsumP) {
  const int bid = blockIdx.x;       // 0..767
  const int q8  = bid & 255;        // CU slot-column; q8%8 = bh%8 = h (XCD pin)
  const int rr  = bid >> 8;         // dispatch round 0..2
  const int bh  = q8 & 31;
  const int jrow = q8 >> 5;         // 0..7
  const int h   = bh & 7;
  const int b   = bh >> 3;
  const uint32_t wi = ATTN_TBL[jrow * 3 + rr];
  const int  t     = wi & 15;
  const int  chnk  = (wi >> 4) & 1;
  const bool split = (wi >> 5) == 2;
  const int  half  = 2 * t + 2;
  const int  st0   = (split && chnk == 1) ? half : 0;
  const int  stN   = (split && chnk == 0) ? half : (4 * t + 4);

  const int tid  = threadIdx.x;
  const int lane = tid & 63;
  const int wv   = tid >> 6;
  const int lo16 = lane & 15;
  const int hi4  = lane >> 4;

  const int qrow0 = t * 128 + wv * 32;   // this wave's 32 q rows (global)
  const int ns_w  = 4 * t + wv + 1;      // causal kv32 limit for this wave

  const size_t bhp = (size_t)(b * NH + h);
  const __hip_bfloat16* Qp = Qw + bhp * S_LEN * DK;
  const __hip_bfloat16* Kp = Kw + bhp * S_LEN * DK;   // tile-blocked images
  const __hip_bfloat16* Vp = Vtw + bhp * S_LEN * DK;  // tile-blocked images

  __shared__ __align__(16) __hip_bfloat16 Ksm[2][32 * 128];  // [dchunk16][kv32][8]
  __shared__ __align__(16) __hip_bfloat16 Vsm[2][128 * 32];  // [kvchunk4][d128][8]
  __shared__ __align__(16) __hip_bfloat16 Psm[4][32 * 40];   // per-wave P

  // Q fragments: A[m=lo16][k=hi4*8+j]; 2 m-groups x 4 k-steps cover 32q x 128d
  bf16x8 qf[2][4];
  for (int m = 0; m < 2; ++m)
    for (int kk = 0; kk < 4; ++kk)
      qf[m][kk] = *(const bf16x8*)&Qp[(size_t)(qrow0 + m * 16 + lo16) * DK +
                                      kk * 32 + hi4 * 8];

  f32x4 oacc[2][8];
  const f32x4 z4 = {0.f, 0.f, 0.f, 0.f};
  for (int m = 0; m < 2; ++m)
    for (int j = 0; j < 8; ++j) oacc[m][j] = z4;
  float lsum[2][4];
  for (int m = 0; m < 2; ++m)
    for (int i = 0; i < 4; ++i) lsum[m][i] = 0.f;

  // staging: tile st is 8KB contiguous at Kp + st*4096 elems; lane c reads
  // c*16B -> fully coalesced 512-lane block copy. Same for V.
  const __hip_bfloat16* kbase[2];
  const __hip_bfloat16* vbase[2];
#pragma unroll
  for (int it = 0; it < 2; ++it) {
    const int c = it * 256 + tid;
    kbase[it] = Kp + (size_t)c * 8;
    vbase[it] = Vp + (size_t)c * 8;
  }
  auto stage = [&](int st, int buf) {
#pragma unroll
    for (int it = 0; it < 2; ++it) {
      const int cb = (it * 256 + wv * 64) * 8;
      gld_lds16(kbase[it] + ((size_t)st << 12), &Ksm[buf][cb]);
      gld_lds16(vbase[it] + ((size_t)st << 12), &Vsm[buf][cb]);
    }
  };

  stage(st0, 0);

  int bsel = 0;
  for (int st = st0; st < stN; ++st) {
    // tile st's 4 loads were issued one full compute phase ago
    asm volatile("s_waitcnt vmcnt(0)" ::: "memory");
    __builtin_amdgcn_s_barrier();
    asm volatile("" ::: "memory");  // no LDS reads hoist above the barrier
    // prefetch next tile into the buffer everyone finished reading at st-1
    if (st + 1 < stN) stage(st + 1, bsel ^ 1);

    if (st < ns_w) {
      const __hip_bfloat16* Kb = Ksm[bsel];
      const __hip_bfloat16* Vb = Vsm[bsel];

      // QK^T: S[32q][32kv] as 2m x 2kn 16x16 tiles
      bf16x8 kf[2][4];
      for (int kn = 0; kn < 2; ++kn)
        for (int kk = 0; kk < 4; ++kk)
          kf[kn][kk] = *(const bf16x8*)&Kb[((kk * 4 + hi4) * 32 + kn * 16 + lo16) * 8];
      f32x4 sc[2][2];
      for (int m = 0; m < 2; ++m)
        for (int kn = 0; kn < 2; ++kn) {
          f32x4 s4 = z4;
          for (int kk = 0; kk < 4; ++kk)
            s4 = mfma16(qf[m][kk], kf[kn][kk], s4);
          sc[m][kn] = s4;
        }

      // constant-max softmax; C/D row = hi4*4+reg, col = lo16
      const int kv0 = st << 5;
      const bool do_mask = (st == ns_w - 1);  // only the diagonal step masks
      for (int m = 0; m < 2; ++m) {
        for (int i = 0; i < 4; ++i) {
          const int qg = qrow0 + m * 16 + hi4 * 4 + i;
          float s0 = sc[m][0][i];
          float s1 = sc[m][1][i];
          if (do_mask) {
            if (kv0 + lo16 > qg)      s0 = -1.0e30f;
            if (kv0 + 16 + lo16 > qg) s1 = -1.0e30f;
          }
          const float p0 = __expf(s0 - 8.f);
          const float p1 = __expf(s1 - 8.f);
          lsum[m][i] += p0 + p1;
          const int prw = m * 16 + hi4 * 4 + i;
          Psm[wv][prw * 40 + lo16]      = __float2bfloat16(p0);
          Psm[wv][prw * 40 + 16 + lo16] = __float2bfloat16(p1);
        }
      }
      // wave-local LDS round-trip: order + drain without any barrier
      asm volatile("s_waitcnt lgkmcnt(0)" ::: "memory");

      // PV: A = P[q16][kv32] per m-group, B = Vt[d][kv]; V frags shared by m
      bf16x8 pf[2];
      for (int m = 0; m < 2; ++m)
        pf[m] = *(const bf16x8*)&Psm[wv][(m * 16 + lo16) * 40 + hi4 * 8];
      for (int j = 0; j < 8; ++j) {
        const bf16x8 vf = *(const bf16x8*)&Vb[(hi4 * 128 + j * 16 + lo16) * 8];
        oacc[0][j] = mfma16(pf[0], vf, oacc[0][j]);
        oacc[1][j] = mfma16(pf[1], vf, oacc[1][j]);
      }
    }
    bsel ^= 1;
  }

  // epilogue: row-sum reduce over 16-lane groups, then either normalized
  // bf16 O (whole-tile blocks) or fp32 partials (split-tile blocks).
  for (int m = 0; m < 2; ++m) {
    for (int i = 0; i < 4; ++i) {
      float l = lsum[m][i];
      l += __shfl_xor(l, 1);
      l += __shfl_xor(l, 2);
      l += __shfl_xor(l, 4);
      l += __shfl_xor(l, 8);
      const int row = wv * 32 + m * 16 + hi4 * 4 + i;   // row within tile
      if (!split) {
        const float inv = 1.0f / l;
        const int qg = t * 128 + row;
        __hip_bfloat16* orow = Og + ((size_t)b * S_LEN + qg) * D_MODEL + h * DK;
        for (int j = 0; j < 8; ++j)
          orow[j * 16 + lo16] = __float2bfloat16(oacc[m][j][i] * inv);
      } else {
        const int pidx = bh * 8 + (t - 8);               // 0..255
        float* prow = partO +
            (((size_t)chnk * 256 + pidx) * 128 + row) * 128;
        for (int j = 0; j < 8; ++j)
          prow[j * 16 + lo16] = oacc[m][j][i];
        if (lo16 == 0)
          lsumP[(chnk * 256 + pidx) * 128 + row] = l;
      }
    }
  }
}

// ---------------------------------------------------------------------------
// Kernel 3: residual + LayerNorm, one block per row. Rows in tiles 8..15
// additionally combine the two split-KV partials: (p0+p1)/(l0+l1).
// ---------------------------------------------------------------------------
__global__ __launch_bounds__(256) void ln_kernel(
    const __hip_bfloat16* __restrict__ Og, const float* __restrict__ partO,
    const float* __restrict__ lsumP, const float* __restrict__ resid_in,
    const float* __restrict__ gamma, const float* __restrict__ beta,
    float* __restrict__ out) {
  const int row  = blockIdx.x;          // 0..8191
  const int b    = row >> 11;
  const int srow = row & (S_LEN - 1);
  const int tile = srow >> 7;
  const int tid  = threadIdx.x;
  const int base = tid * 4;
  const float4 q4 = *(const float4*)(resid_in + (size_t)row * D_MODEL + base);
  float v[4];
  if (tile < 8) {
    const __hip_bfloat16* orow = Og + (size_t)row * D_MODEL;
    const ushort4 o4 = *(const ushort4*)(orow + base);
    v[0] = __bfloat162float(*(const __hip_bfloat16*)&o4.x) + q4.x;
    v[1] = __bfloat162float(*(const __hip_bfloat16*)&o4.y) + q4.y;
    v[2] = __bfloat162float(*(const __hip_bfloat16*)&o4.z) + q4.z;
    v[3] = __bfloat162float(*(const __hip_bfloat16*)&o4.w) + q4.w;
  } else {
    const int h    = base >> 7;
    const int rin  = srow & 127;
    const int pidx = (b * 8 + h) * 8 + (tile - 8);
    const size_t off = ((size_t)pidx * 128 + rin) * 128 + (base & 127);
    const float4 p0 = *(const float4*)(partO + off);
    const float4 p1 = *(const float4*)(partO + (size_t)256 * 128 * 128 + off);
    const float l = lsumP[pidx * 128 + rin] +
                    lsumP[256 * 128 + pidx * 128 + rin];
    const float inv = 1.0f / l;
    v[0] = (p0.x + p1.x) * inv + q4.x;
    v[1] = (p0.y + p1.y) * inv + q4.y;
    v[2] = (p0.z + p1.z) * inv + q4.z;
    v[3] = (p0.w + p1.w) * inv + q4.w;
  }
  float s = v[0] + v[1] + v[2] + v[3];
  float ss = v[0] * v[0] + v[1] * v[1] + v[2] * v[2] + v[3] * v[3];
  for (int m = 1; m < 64; m <<= 1) { s += __shfl_xor(s, m); ss += __shfl_xor(ss, m); }
  __shared__ float red[8];
  const int wv = tid >> 6, lane = tid & 63;
  if (lane == 0) { red[wv] = s; red[4 + wv] = ss; }
  __syncthreads();
  s  = red[0] + red[1] + red[2] + red[3];
  ss = red[4] + red[5] + red[6] + red[7];
  const float mu  = s * (1.0f / D_MODEL);
  const float var = ss * (1.0f / D_MODEL) - mu * mu;
  const float rstd = rsqrtf(var + 1e-6f);
  const float4 g4 = *(const float4*)(gamma + base);
  const float4 b4 = *(const float4*)(beta + base);
  float4 o;
  o.x = (v[0] - mu) * rstd * g4.x + b4.x;
  o.y = (v[1] - mu) * rstd * g4.y + b4.y;
  o.z = (v[2] - mu) * rstd * g4.z + b4.z;
  o.w = (v[3] - mu) * rstd * g4.w + b4.w;
  *(float4*)(out + (size_t)row * D_MODEL + base) = o;
}

// ---------------------------------------------------------------------------
extern "C" void kernel_launch(void* const* d_in, const int* in_sizes, int n_in,
                              void* d_out, int out_size, void* d_ws, size_t ws_size,
                              hipStream_t stream) {
  const float* queries = (const float*)d_in[0];
  const float* keys    = (const float*)d_in[1];
  const float* values  = (const float*)d_in[2];
  const float* Wq = (const float*)d_in[3];
  const float* bq = (const float*)d_in[4];
  const float* Wk = (const float*)d_in[5];
  const float* bk = (const float*)d_in[6];
  const float* Wv = (const float*)d_in[7];
  const float* bv = (const float*)d_in[8];
  const float* gamma = (const float*)d_in[9];
  const float* beta  = (const float*)d_in[10];

  char* ws = (char*)d_ws;
  const size_t N = (size_t)BATCH * S_LEN * D_MODEL;                 // 8M
  const size_t WT_BYTES  = (size_t)3 * D_MODEL * D_MODEL * 2;      // 6 MB
  const size_t XBF_BYTES = (size_t)3 * N * 2;                      // 48 MB
  const size_t QKV_BYTES = (size_t)BATCH * NH * S_LEN * DK * 2;    // 16 MB
  const size_t OG_BYTES  = (size_t)BATCH * S_LEN * D_MODEL * 2;    // 16 MB
  __hip_bfloat16* Wt  = (__hip_bfloat16*)ws;
  __hip_bfloat16* Xbf = (__hip_bfloat16*)(ws + WT_BYTES);
  // After qkv_gemm, the Xbf (48MB) and Wt (6MB) regions are dead:
  //   Og   bf16 16MB  @ XBF+0      (rows of tiles 0..7 only)
  //   partO f32 32MB  @ XBF+16MB   ([2 splits][256 pidx][128 row][128 d])
  //   lsumP f32 256KB @ ws+0       ([2 splits][256 pidx][128 row])
  __hip_bfloat16* Ogs = (__hip_bfloat16*)(ws + WT_BYTES);
  float* partO = (float*)(ws + WT_BYTES + OG_BYTES);
  float* lsumP = (float*)ws;
  __hip_bfloat16* Qws = (__hip_bfloat16*)(ws + WT_BYTES + XBF_BYTES);
  __hip_bfloat16* Kws = (__hip_bfloat16*)(ws + WT_BYTES + XBF_BYTES + QKV_BYTES);
  __hip_bfloat16* Vws = (__hip_bfloat16*)(ws + WT_BYTES + XBF_BYTES + 2 * QKV_BYTES);

  cvt_kernel<<<dim3((unsigned)(N / 1024), 3), 256, 0, stream>>>(queries, keys, values, Xbf);
  wtrans_kernel<<<dim3(32, 32, 3), dim3(32, 8), 0, stream>>>(Wq, Wk, Wv, Wt);
  qkv_gemm_kernel<<<dim3(1536), 256, 0, stream>>>(
      Xbf, bq, bk, bv, Wt, Qws, Kws, Vws);
  attn_kernel<<<dim3(768), 256, 0, stream>>>(Qws, Kws, Vws, Ogs, partO, lsumP);
  ln_kernel<<<dim3(BATCH * S_LEN), 256, 0, stream>>>(Ogs, partO, lsumP, queries,
                                                     gamma, beta, (float*)d_out);
}

// Round 4
// 324.995 us; speedup vs baseline: 1.1925x; 1.0693x over previous
//
#include <hip/hip_runtime.h>
#include <hip/hip_bf16.h>
#include <stdint.h>

#define D_MODEL 1024
#define S_LEN   2048
#define BATCH   4
#define NH      8
#define DK      128

typedef __attribute__((ext_vector_type(8))) __bf16 bf16x8;
typedef __attribute__((ext_vector_type(4))) float  f32x4;

__device__ __forceinline__ f32x4 mfma16(bf16x8 a, bf16x8 b, f32x4 c) {
  return __builtin_amdgcn_mfma_f32_16x16x32_bf16(a, b, c, 0, 0, 0);
}

// async global->LDS, 16B per lane; lds base is wave-uniform, HW writes
// ldsbase + lane*16 (guide §5, m97/m104).
__device__ __forceinline__ void gld_lds16(const void* g, void* l) {
  __builtin_amdgcn_global_load_lds(
      (const __attribute__((address_space(1))) void*)g,
      (__attribute__((address_space(3))) void*)l, 16, 0, 0);
}

#define ATTN_SCALE 0.08838834764831845f  // 1/sqrt(128), folded into Wq/bq

// ---------------------------------------------------------------------------
// Kernel 0a: fp32 -> bf16 convert of the three activation tensors.
// ---------------------------------------------------------------------------
__global__ __launch_bounds__(256) void cvt_kernel(
    const float* __restrict__ x0, const float* __restrict__ x1,
    const float* __restrict__ x2, __hip_bfloat16* __restrict__ out) {
  const size_t N = (size_t)BATCH * S_LEN * D_MODEL;  // 8M elems
  const int w = blockIdx.y;
  const float* src = (w == 0) ? x0 : (w == 1) ? x1 : x2;
  __hip_bfloat16* dst = out + (size_t)w * N;
  const size_t i = ((size_t)blockIdx.x * 256 + threadIdx.x) * 4;
  const float4 v = *(const float4*)(src + i);
  *(__hip_bfloat162*)(dst + i)     = __float22bfloat162_rn(make_float2(v.x, v.y));
  *(__hip_bfloat162*)(dst + i + 2) = __float22bfloat162_rn(make_float2(v.z, v.w));
}

// ---------------------------------------------------------------------------
// Kernel 0b: transpose+convert weights W[k][n] fp32 -> Wt[n][k] bf16.
// Wq pre-scaled by 1/sqrt(dk).
// ---------------------------------------------------------------------------
__global__ void wtrans_kernel(const float* __restrict__ Wq,
                              const float* __restrict__ Wk,
                              const float* __restrict__ Wv,
                              __hip_bfloat16* __restrict__ Wt) {
  __shared__ __hip_bfloat16 tile[32][33];
  const int w = blockIdx.z;
  const float* src = (w == 0) ? Wq : (w == 1) ? Wk : Wv;
  const float sc = (w == 0) ? ATTN_SCALE : 1.0f;
  __hip_bfloat16* dst = Wt + (size_t)w * D_MODEL * D_MODEL;
  const int tx = threadIdx.x, ty = threadIdx.y;
  int x = blockIdx.x * 32 + tx;
  int y = blockIdx.y * 32 + ty;
  for (int i = 0; i < 32; i += 8)
    tile[ty + i][tx] = __float2bfloat16(src[(size_t)(y + i) * D_MODEL + x] * sc);
  __syncthreads();
  x = blockIdx.y * 32 + tx;
  y = blockIdx.x * 32 + ty;
  for (int i = 0; i < 32; i += 8)
    dst[(size_t)(y + i) * D_MODEL + x] = tile[tx][ty + i];
}

// ---------------------------------------------------------------------------
// Kernel 1: QKV projection GEMM. R4 changes:
//  - BK=64 (half the barriers/vmcnt drains of BK=32).
//  - XOR-swizzled staging (rule #21: linear LDS dest via gld_lds, the SOURCE
//    address carries the inverse swizzle, frag reads apply the same XOR).
//    Kills the 8-way quarter-wave bank conflict of the old stride-64B reads.
//  - LDS-repack epilogue: acc -> Cbuf (aliases dead staging LDS) -> 8
//    coalesced b128 global stores/thread in the exact Q/K/V image order
//    (was 64 scattered 2B stores).
// Images: Q natural [bh][s][dk].
//  K: Kb[bh][t32][d>>3][s&31][d&7]  (8KB per kv32-tile, = attn LDS image)
//  V: Vb[bh][t32][slot>>3][d][slot&7], slot = 2*(s&15) + ((s>>4)&1)
//     (kv-interleaved so attn's packed-pair P writes line up; see attn).
// ---------------------------------------------------------------------------
__global__ __launch_bounds__(256) void qkv_gemm_kernel(
    const __hip_bfloat16* __restrict__ Xbf,
    const float* __restrict__ bq, const float* __restrict__ bk,
    const float* __restrict__ bv,
    const __hip_bfloat16* __restrict__ Wt,
    __hip_bfloat16* __restrict__ Qo, __hip_bfloat16* __restrict__ Ko,
    __hip_bfloat16* __restrict__ Vo) {
  const int flat = blockIdx.x;          // 0..1535
  const int xcd  = flat & 7;
  const int idx  = flat >> 3;           // 0..191
  const int n_t  = idx & 7;
  const int mg   = idx >> 3;            // 0..23
  const int pair = xcd * 24 + mg;       // 0..191 = 64 m-tiles x 3 slices
  const int which = pair >> 6;
  const int m_t   = pair & 63;

  const size_t N = (size_t)BATCH * S_LEN * D_MODEL;
  const __hip_bfloat16* X = Xbf + (size_t)which * N;
  const __hip_bfloat16* W = Wt + (size_t)which * D_MODEL * D_MODEL;
  const float* bias = (which == 0) ? bq : (which == 1) ? bk : bv;
  const float bscale = (which == 0) ? ATTN_SCALE : 1.0f;

  // staging (2 x 16KB) and epilogue Cbuf (34KB) share the same LDS
  __shared__ __align__(16) char smem[128 * 136 * 2];
  __hip_bfloat16* Asm = (__hip_bfloat16*)smem;   // [128][64]
  __hip_bfloat16* Bsm = Asm + 128 * 64;          // [128][64]
  __hip_bfloat16* Cb  = (__hip_bfloat16*)smem;   // [128][136]

  const int tid  = threadIdx.x;
  const int lane = tid & 63;
  const int wv   = tid >> 6;
  const int lo16 = lane & 15;
  const int hi4  = lane >> 4;
  const int m0 = m_t * 128;
  const int n0 = n_t * 128;
  const int wm = (wv >> 1) * 64;
  const int wn = (wv & 1) * 64;

  f32x4 acc[4][4];
  const f32x4 z4 = {0.f, 0.f, 0.f, 0.f};
  for (int i = 0; i < 4; ++i)
    for (int j = 0; j < 4; ++j) acc[i][j] = z4;

  for (int k0 = 0; k0 < D_MODEL; k0 += 64) {
    __syncthreads();
    for (int it = 0; it < 4; ++it) {
      const int cbase = it * 256 + wv * 64;
      const int c = cbase + lane;
      const int row = c >> 3;
      const int kc = ((c & 7) ^ (row & 7)) * 8;   // inverse swizzle on source
      gld_lds16(X + (size_t)(m0 + row) * D_MODEL + k0 + kc, &Asm[cbase * 8]);
      gld_lds16(W + (size_t)(n0 + row) * D_MODEL + k0 + kc, &Bsm[cbase * 8]);
    }
    __syncthreads();

    for (int kk = 0; kk < 2; ++kk) {
      bf16x8 af[4], bfr[4];
      const int sl = (kk * 4 + hi4);
      for (int i = 0; i < 4; ++i) {
        const int lm = wm + 16 * i + lo16;
        af[i] = *(const bf16x8*)&Asm[lm * 64 + ((sl ^ (lm & 7)) * 8)];
      }
      for (int j = 0; j < 4; ++j) {
        const int ln = wn + 16 * j + lo16;
        bfr[j] = *(const bf16x8*)&Bsm[ln * 64 + ((sl ^ (ln & 7)) * 8)];
      }
      for (int i = 0; i < 4; ++i)
        for (int j = 0; j < 4; ++j)
          acc[i][j] = mfma16(af[i], bfr[j], acc[i][j]);
    }
  }

  // ---- epilogue: repack through LDS, then coalesced b128 stores ----
  const int b  = m0 >> 11;
  const int s0 = m0 & (S_LEN - 1);
  const int h  = n0 >> 7;                 // n-tile == one head
  const size_t bh = (size_t)(b * NH + h);

  __syncthreads();                        // protect last frag reads
  for (int j = 0; j < 4; ++j) {
    const int nl = wn + 16 * j + lo16;    // local d
    const float bval = bias[n0 + nl] * bscale;
    for (int i = 0; i < 4; ++i) {
      for (int r = 0; r < 4; ++r) {
        const int lm = wm + 16 * i + hi4 * 4 + r;   // local token row
        const __hip_bfloat16 ob = __float2bfloat16(acc[i][j][r] + bval);
        if (which == 2) {
          // transposed + slot-permuted: Cb[d][(lm&96) + slot]
          const int col = (lm & 96) + 2 * (lm & 15) + ((lm >> 4) & 1);
          Cb[nl * 136 + col] = ob;
        } else {
          Cb[lm * 136 + nl] = ob;
        }
      }
    }
  }
  __syncthreads();

  if (which == 0) {
    __hip_bfloat16* gq = Qo + (bh * S_LEN + s0) * DK;
    for (int r8 = 0; r8 < 8; ++r8) {
      const int C = r8 * 256 + tid;                  // 0..2047
      const bf16x8 v = *(const bf16x8*)&Cb[(C >> 4) * 136 + (C & 15) * 8];
      *(bf16x8*)&gq[(size_t)C * 8] = v;
    }
  } else if (which == 1) {
    __hip_bfloat16* gk = Ko + (bh * 64 + (s0 >> 5)) * 4096;
    for (int r8 = 0; r8 < 8; ++r8) {
      const int C = r8 * 256 + tid;
      const int su = C >> 9, Cw = C & 511;
      const bf16x8 v =
          *(const bf16x8*)&Cb[(su * 32 + (Cw & 31)) * 136 + (Cw >> 5) * 8];
      *(bf16x8*)&gk[(size_t)su * 4096 + (Cw >> 5) * 256 + (Cw & 31) * 8] = v;
    }
  } else {
    __hip_bfloat16* gv = Vo + (bh * 64 + (s0 >> 5)) * 4096;
    for (int r8 = 0; r8 < 8; ++r8) {
      const int C = r8 * 256 + tid;
      const int su = C >> 9, Cw = C & 511;
      const bf16x8 v =
          *(const bf16x8*)&Cb[(C & 127) * 136 + su * 32 + (Cw >> 7) * 8];
      *(bf16x8*)&gv[(size_t)su * 4096 + (size_t)Cw * 8] = v;
    }
  }
}

// ---------------------------------------------------------------------------
// Kernel 2: causal flash attention, SPLIT-KV + balanced-triple schedule +
// coalesced tile-blocked staging. R4: packed P writes (8 x b32 pair writes
// instead of 16 scalar b16) against the kv-interleaved V image — the PV
// reduction runs in permuted kv order on BOTH operands (order-invariant).
// LDS-throughput is the measured bottleneck (~3.7k cyc/CU/step).
// ---------------------------------------------------------------------------
__device__ const uint32_t ATTN_TBL[24] = {
  // pack = tile | chunk<<4 | nchunks<<5 ; rows j=0..7, cols r=0..2
  79, 95, 32,   // t15h0(32) t15h1(32) t0(4)
  78, 94, 33,   // t14h0(30) t14h1(30) t1(8)
  77, 93, 34,   // t13h0(28) t13h1(28) t2(12)
  76, 92, 35,   // t12h0(26) t12h1(26) t3(16)
  75, 91, 36,   // t11h0(24) t11h1(24) t4(20)
  39, 72, 88,   // t7(32)    t8h0(18)  t8h1(18)
  38, 73, 89,   // t6(28)    t9h0(20)  t9h1(20)
  37, 74, 90    // t5(24)    t10h0(22) t10h1(22)
};

__global__ __launch_bounds__(256) void attn_kernel(
    const __hip_bfloat16* __restrict__ Qw, const __hip_bfloat16* __restrict__ Kw,
    const __hip_bfloat16* __restrict__ Vtw, __hip_bfloat16* __restrict__ Og,
    float* __restrict__ partO, float* __restrict__ lsumP) {
  const int bid = blockIdx.x;       // 0..767
  const int q8  = bid & 255;        // CU slot-column; q8%8 = bh%8 = h (XCD pin)
  const int rr  = bid >> 8;         // dispatch round 0..2
  const int bh  = q8 & 31;
  const int jrow = q8 >> 5;         // 0..7
  const int h   = bh & 7;
  const int b   = bh >> 3;
  const uint32_t wi = ATTN_TBL[jrow * 3 + rr];
  const int  t     = wi & 15;
  const int  chnk  = (wi >> 4) & 1;
  const bool split = (wi >> 5) == 2;
  const int  half  = 2 * t + 2;
  const int  st0   = (split && chnk == 1) ? half : 0;
  const int  stN   = (split && chnk == 0) ? half : (4 * t + 4);

  const int tid  = threadIdx.x;
  const int lane = tid & 63;
  const int wv   = tid >> 6;
  const int lo16 = lane & 15;
  const int hi4  = lane >> 4;

  const int qrow0 = t * 128 + wv * 32;   // this wave's 32 q rows (global)
  const int ns_w  = 4 * t + wv + 1;      // causal kv32 limit for this wave

  const size_t bhp = (size_t)(b * NH + h);
  const __hip_bfloat16* Qp = Qw + bhp * S_LEN * DK;
  const __hip_bfloat16* Kp = Kw + bhp * S_LEN * DK;   // tile-blocked images
  const __hip_bfloat16* Vp = Vtw + bhp * S_LEN * DK;  // tile-blocked images

  __shared__ __align__(16) __hip_bfloat16 Ksm[2][32 * 128];  // [d16][kv32][8]
  __shared__ __align__(16) __hip_bfloat16 Vsm[2][128 * 32];  // [slot4][d128][8]
  __shared__ __align__(16) __hip_bfloat16 Psm[4][32 * 40];   // per-wave P (pairs)

  // Q fragments: A[m=lo16][k=hi4*8+j]; 2 m-groups x 4 k-steps cover 32q x 128d
  bf16x8 qf[2][4];
  for (int m = 0; m < 2; ++m)
    for (int kk = 0; kk < 4; ++kk)
      qf[m][kk] = *(const bf16x8*)&Qp[(size_t)(qrow0 + m * 16 + lo16) * DK +
                                      kk * 32 + hi4 * 8];

  f32x4 oacc[2][8];
  const f32x4 z4 = {0.f, 0.f, 0.f, 0.f};
  for (int m = 0; m < 2; ++m)
    for (int j = 0; j < 8; ++j) oacc[m][j] = z4;
  float lsum[2][4];
  for (int m = 0; m < 2; ++m)
    for (int i = 0; i < 4; ++i) lsum[m][i] = 0.f;

  // staging: tile st is 8KB contiguous; lane c reads c*16B -> coalesced.
  const __hip_bfloat16* kbase[2];
  const __hip_bfloat16* vbase[2];
#pragma unroll
  for (int it = 0; it < 2; ++it) {
    const int c = it * 256 + tid;
    kbase[it] = Kp + (size_t)c * 8;
    vbase[it] = Vp + (size_t)c * 8;
  }
  auto stage = [&](int st, int buf) {
#pragma unroll
    for (int it = 0; it < 2; ++it) {
      const int cb = (it * 256 + wv * 64) * 8;
      gld_lds16(kbase[it] + ((size_t)st << 12), &Ksm[buf][cb]);
      gld_lds16(vbase[it] + ((size_t)st << 12), &Vsm[buf][cb]);
    }
  };

  stage(st0, 0);

  int bsel = 0;
  for (int st = st0; st < stN; ++st) {
    // tile st's 4 loads were issued one full compute phase ago
    asm volatile("s_waitcnt vmcnt(0)" ::: "memory");
    __builtin_amdgcn_s_barrier();
    asm volatile("" ::: "memory");  // no LDS reads hoist above the barrier
    // prefetch next tile into the buffer everyone finished reading at st-1
    if (st + 1 < stN) stage(st + 1, bsel ^ 1);

    if (st < ns_w) {
      const __hip_bfloat16* Kb = Ksm[bsel];
      const __hip_bfloat16* Vb = Vsm[bsel];

      // QK^T: S[32q][32kv] as 2m x 2kn 16x16 tiles
      bf16x8 kf[2][4];
      for (int kn = 0; kn < 2; ++kn)
        for (int kk = 0; kk < 4; ++kk)
          kf[kn][kk] = *(const bf16x8*)&Kb[((kk * 4 + hi4) * 32 + kn * 16 + lo16) * 8];
      f32x4 sc[2][2];
      for (int m = 0; m < 2; ++m)
        for (int kn = 0; kn < 2; ++kn) {
          f32x4 s4 = z4;
          for (int kk = 0; kk < 4; ++kk)
            s4 = mfma16(qf[m][kk], kf[kn][kk], s4);
          sc[m][kn] = s4;
        }

      // constant-max softmax; C/D row = hi4*4+reg, col = lo16.
      // P pair (kv=lo16, kv=16+lo16) packed into one b32 write at col 2*lo16
      // (kv-interleaved slot order, matching the V image).
      const int kv0 = st << 5;
      const bool do_mask = (st == ns_w - 1);  // only the diagonal step masks
      for (int m = 0; m < 2; ++m) {
        for (int i = 0; i < 4; ++i) {
          const int qg = qrow0 + m * 16 + hi4 * 4 + i;
          float s0 = sc[m][0][i];
          float s1 = sc[m][1][i];
          if (do_mask) {
            if (kv0 + lo16 > qg)      s0 = -1.0e30f;
            if (kv0 + 16 + lo16 > qg) s1 = -1.0e30f;
          }
          const float p0 = __expf(s0 - 8.f);
          const float p1 = __expf(s1 - 8.f);
          lsum[m][i] += p0 + p1;
          const int prw = m * 16 + hi4 * 4 + i;
          *(__hip_bfloat162*)&Psm[wv][prw * 40 + 2 * lo16] =
              __float22bfloat162_rn(make_float2(p0, p1));
        }
      }
      // wave-local LDS round-trip: order + drain without any barrier
      asm volatile("s_waitcnt lgkmcnt(0)" ::: "memory");

      // PV: A = P[q16][slot32] per m-group, B = V[d][slot]; shared by m
      bf16x8 pf[2];
      for (int m = 0; m < 2; ++m)
        pf[m] = *(const bf16x8*)&Psm[wv][(m * 16 + lo16) * 40 + hi4 * 8];
      for (int j = 0; j < 8; ++j) {
        const bf16x8 vf = *(const bf16x8*)&Vb[(hi4 * 128 + j * 16 + lo16) * 8];
        oacc[0][j] = mfma16(pf[0], vf, oacc[0][j]);
        oacc[1][j] = mfma16(pf[1], vf, oacc[1][j]);
      }
    }
    bsel ^= 1;
  }

  // epilogue: row-sum reduce over 16-lane groups, then either normalized
  // bf16 O (whole-tile blocks) or fp32 partials (split-tile blocks).
  for (int m = 0; m < 2; ++m) {
    for (int i = 0; i < 4; ++i) {
      float l = lsum[m][i];
      l += __shfl_xor(l, 1);
      l += __shfl_xor(l, 2);
      l += __shfl_xor(l, 4);
      l += __shfl_xor(l, 8);
      const int row = wv * 32 + m * 16 + hi4 * 4 + i;   // row within tile
      if (!split) {
        const float inv = 1.0f / l;
        const int qg = t * 128 + row;
        __hip_bfloat16* orow = Og + ((size_t)b * S_LEN + qg) * D_MODEL + h * DK;
        for (int j = 0; j < 8; ++j)
          orow[j * 16 + lo16] = __float2bfloat16(oacc[m][j][i] * inv);
      } else {
        const int pidx = bh * 8 + (t - 8);               // 0..255
        float* prow = partO +
            (((size_t)chnk * 256 + pidx) * 128 + row) * 128;
        for (int j = 0; j < 8; ++j)
          prow[j * 16 + lo16] = oacc[m][j][i];
        if (lo16 == 0)
          lsumP[(chnk * 256 + pidx) * 128 + row] = l;
      }
    }
  }
}

// ---------------------------------------------------------------------------
// Kernel 3: residual + LayerNorm, one block per row. Rows in tiles 8..15
// additionally combine the two split-KV partials: (p0+p1)/(l0+l1).
// ---------------------------------------------------------------------------
__global__ __launch_bounds__(256) void ln_kernel(
    const __hip_bfloat16* __restrict__ Og, const float* __restrict__ partO,
    const float* __restrict__ lsumP, const float* __restrict__ resid_in,
    const float* __restrict__ gamma, const float* __restrict__ beta,
    float* __restrict__ out) {
  const int row  = blockIdx.x;          // 0..8191
  const int b    = row >> 11;
  const int srow = row & (S_LEN - 1);
  const int tile = srow >> 7;
  const int tid  = threadIdx.x;
  const int base = tid * 4;
  const float4 q4 = *(const float4*)(resid_in + (size_t)row * D_MODEL + base);
  float v[4];
  if (tile < 8) {
    const __hip_bfloat16* orow = Og + (size_t)row * D_MODEL;
    const ushort4 o4 = *(const ushort4*)(orow + base);
    v[0] = __bfloat162float(*(const __hip_bfloat16*)&o4.x) + q4.x;
    v[1] = __bfloat162float(*(const __hip_bfloat16*)&o4.y) + q4.y;
    v[2] = __bfloat162float(*(const __hip_bfloat16*)&o4.z) + q4.z;
    v[3] = __bfloat162float(*(const __hip_bfloat16*)&o4.w) + q4.w;
  } else {
    const int h    = base >> 7;
    const int rin  = srow & 127;
    const int pidx = (b * 8 + h) * 8 + (tile - 8);
    const size_t off = ((size_t)pidx * 128 + rin) * 128 + (base & 127);
    const float4 p0 = *(const float4*)(partO + off);
    const float4 p1 = *(const float4*)(partO + (size_t)256 * 128 * 128 + off);
    const float l = lsumP[pidx * 128 + rin] +
                    lsumP[256 * 128 + pidx * 128 + rin];
    const float inv = 1.0f / l;
    v[0] = (p0.x + p1.x) * inv + q4.x;
    v[1] = (p0.y + p1.y) * inv + q4.y;
    v[2] = (p0.z + p1.z) * inv + q4.z;
    v[3] = (p0.w + p1.w) * inv + q4.w;
  }
  float s = v[0] + v[1] + v[2] + v[3];
  float ss = v[0] * v[0] + v[1] * v[1] + v[2] * v[2] + v[3] * v[3];
  for (int m = 1; m < 64; m <<= 1) { s += __shfl_xor(s, m); ss += __shfl_xor(ss, m); }
  __shared__ float red[8];
  const int wv = tid >> 6, lane = tid & 63;
  if (lane == 0) { red[wv] = s; red[4 + wv] = ss; }
  __syncthreads();
  s  = red[0] + red[1] + red[2] + red[3];
  ss = red[4] + red[5] + red[6] + red[7];
  const float mu  = s * (1.0f / D_MODEL);
  const float var = ss * (1.0f / D_MODEL) - mu * mu;
  const float rstd = rsqrtf(var + 1e-6f);
  const float4 g4 = *(const float4*)(gamma + base);
  const float4 b4 = *(const float4*)(beta + base);
  float4 o;
  o.x = (v[0] - mu) * rstd * g4.x + b4.x;
  o.y = (v[1] - mu) * rstd * g4.y + b4.y;
  o.z = (v[2] - mu) * rstd * g4.z + b4.z;
  o.w = (v[3] - mu) * rstd * g4.w + b4.w;
  *(float4*)(out + (size_t)row * D_MODEL + base) = o;
}

// ---------------------------------------------------------------------------
extern "C" void kernel_launch(void* const* d_in, const int* in_sizes, int n_in,
                              void* d_out, int out_size, void* d_ws, size_t ws_size,
                              hipStream_t stream) {
  const float* queries = (const float*)d_in[0];
  const float* keys    = (const float*)d_in[1];
  const float* values  = (const float*)d_in[2];
  const float* Wq = (const float*)d_in[3];
  const float* bq = (const float*)d_in[4];
  const float* Wk = (const float*)d_in[5];
  const float* bk = (const float*)d_in[6];
  const float* Wv = (const float*)d_in[7];
  const float* bv = (const float*)d_in[8];
  const float* gamma = (const float*)d_in[9];
  const float* beta  = (const float*)d_in[10];

  char* ws = (char*)d_ws;
  const size_t N = (size_t)BATCH * S_LEN * D_MODEL;                 // 8M
  const size_t WT_BYTES  = (size_t)3 * D_MODEL * D_MODEL * 2;      // 6 MB
  const size_t XBF_BYTES = (size_t)3 * N * 2;                      // 48 MB
  const size_t QKV_BYTES = (size_t)BATCH * NH * S_LEN * DK * 2;    // 16 MB
  const size_t OG_BYTES  = (size_t)BATCH * S_LEN * D_MODEL * 2;    // 16 MB
  __hip_bfloat16* Wt  = (__hip_bfloat16*)ws;
  __hip_bfloat16* Xbf = (__hip_bfloat16*)(ws + WT_BYTES);
  // After qkv_gemm, the Xbf (48MB) and Wt (6MB) regions are dead:
  //   Og   bf16 16MB  @ XBF+0      (rows of tiles 0..7 only)
  //   partO f32 32MB  @ XBF+16MB   ([2 splits][256 pidx][128 row][128 d])
  //   lsumP f32 256KB @ ws+0       ([2 splits][256 pidx][128 row])
  __hip_bfloat16* Ogs = (__hip_bfloat16*)(ws + WT_BYTES);
  float* partO = (float*)(ws + WT_BYTES + OG_BYTES);
  float* lsumP = (float*)ws;
  __hip_bfloat16* Qws = (__hip_bfloat16*)(ws + WT_BYTES + XBF_BYTES);
  __hip_bfloat16* Kws = (__hip_bfloat16*)(ws + WT_BYTES + XBF_BYTES + QKV_BYTES);
  __hip_bfloat16* Vws = (__hip_bfloat16*)(ws + WT_BYTES + XBF_BYTES + 2 * QKV_BYTES);

  cvt_kernel<<<dim3((unsigned)(N / 1024), 3), 256, 0, stream>>>(queries, keys, values, Xbf);
  wtrans_kernel<<<dim3(32, 32, 3), dim3(32, 8), 0, stream>>>(Wq, Wk, Wv, Wt);
  qkv_gemm_kernel<<<dim3(1536), 256, 0, stream>>>(
      Xbf, bq, bk, bv, Wt, Qws, Kws, Vws);
  attn_kernel<<<dim3(768), 256, 0, stream>>>(Qws, Kws, Vws, Ogs, partO, lsumP);
  ln_kernel<<<dim3(BATCH * S_LEN), 256, 0, stream>>>(Ogs, partO, lsumP, queries,
                                                     gamma, beta, (float*)d_out);
}

// Round 5
// 314.428 us; speedup vs baseline: 1.2326x; 1.0336x over previous
//
#include <hip/hip_runtime.h>
#include <hip/hip_bf16.h>
#include <stdint.h>

#define D_MODEL 1024
#define S_LEN   2048
#define BATCH   4
#define NH      8
#define DK      128

typedef __attribute__((ext_vector_type(8))) __bf16 bf16x8;
typedef __attribute__((ext_vector_type(4))) float  f32x4;

__device__ __forceinline__ f32x4 mfma16(bf16x8 a, bf16x8 b, f32x4 c) {
  return __builtin_amdgcn_mfma_f32_16x16x32_bf16(a, b, c, 0, 0, 0);
}

// async global->LDS, 16B per lane; lds base is wave-uniform, HW writes
// ldsbase + lane*16 (guide §5, m97/m104).
__device__ __forceinline__ void gld_lds16(const void* g, void* l) {
  __builtin_amdgcn_global_load_lds(
      (const __attribute__((address_space(1))) void*)g,
      (__attribute__((address_space(3))) void*)l, 16, 0, 0);
}

#define ATTN_SCALE 0.08838834764831845f  // 1/sqrt(128), folded into Wq/bq

// ---------------------------------------------------------------------------
// Kernel 0a: fp32 -> bf16 convert of the three activation tensors.
// ---------------------------------------------------------------------------
__global__ __launch_bounds__(256) void cvt_kernel(
    const float* __restrict__ x0, const float* __restrict__ x1,
    const float* __restrict__ x2, __hip_bfloat16* __restrict__ out) {
  const size_t N = (size_t)BATCH * S_LEN * D_MODEL;  // 8M elems
  const int w = blockIdx.y;
  const float* src = (w == 0) ? x0 : (w == 1) ? x1 : x2;
  __hip_bfloat16* dst = out + (size_t)w * N;
  const size_t i = ((size_t)blockIdx.x * 256 + threadIdx.x) * 4;
  const float4 v = *(const float4*)(src + i);
  *(__hip_bfloat162*)(dst + i)     = __float22bfloat162_rn(make_float2(v.x, v.y));
  *(__hip_bfloat162*)(dst + i + 2) = __float22bfloat162_rn(make_float2(v.z, v.w));
}

// ---------------------------------------------------------------------------
// Kernel 0b: transpose+convert weights W[k][n] fp32 -> Wt[n][k] bf16.
// Wq pre-scaled by 1/sqrt(dk).
// ---------------------------------------------------------------------------
__global__ void wtrans_kernel(const float* __restrict__ Wq,
                              const float* __restrict__ Wk,
                              const float* __restrict__ Wv,
                              __hip_bfloat16* __restrict__ Wt) {
  __shared__ __hip_bfloat16 tile[32][33];
  const int w = blockIdx.z;
  const float* src = (w == 0) ? Wq : (w == 1) ? Wk : Wv;
  const float sc = (w == 0) ? ATTN_SCALE : 1.0f;
  __hip_bfloat16* dst = Wt + (size_t)w * D_MODEL * D_MODEL;
  const int tx = threadIdx.x, ty = threadIdx.y;
  int x = blockIdx.x * 32 + tx;
  int y = blockIdx.y * 32 + ty;
  for (int i = 0; i < 32; i += 8)
    tile[ty + i][tx] = __float2bfloat16(src[(size_t)(y + i) * D_MODEL + x] * sc);
  __syncthreads();
  x = blockIdx.y * 32 + tx;
  y = blockIdx.x * 32 + ty;
  for (int i = 0; i < 32; i += 8)
    dst[(size_t)(y + i) * D_MODEL + x] = tile[tx][ty + i];
}

// ---------------------------------------------------------------------------
// Kernel 1: QKV projection GEMM. BK=64, XOR-swizzled staging (both sides),
// LDS-repack epilogue with coalesced b128 stores.
// Images: Q natural [bh][s][dk].
//  K: Kb[bh][t32][d>>3][s&31][d&7]  (8KB per kv32-tile, = attn LDS image)
//  V: Vb[bh][t32][slot>>3][d][slot&7], slot = 2*(s&15) + ((s>>4)&1)
//     (kv-interleaved so attn's packed-pair P writes line up).
// ---------------------------------------------------------------------------
__global__ __launch_bounds__(256) void qkv_gemm_kernel(
    const __hip_bfloat16* __restrict__ Xbf,
    const float* __restrict__ bq, const float* __restrict__ bk,
    const float* __restrict__ bv,
    const __hip_bfloat16* __restrict__ Wt,
    __hip_bfloat16* __restrict__ Qo, __hip_bfloat16* __restrict__ Ko,
    __hip_bfloat16* __restrict__ Vo) {
  const int flat = blockIdx.x;          // 0..1535
  const int xcd  = flat & 7;
  const int idx  = flat >> 3;           // 0..191
  const int n_t  = idx & 7;
  const int mg   = idx >> 3;            // 0..23
  const int pair = xcd * 24 + mg;       // 0..191 = 64 m-tiles x 3 slices
  const int which = pair >> 6;
  const int m_t   = pair & 63;

  const size_t N = (size_t)BATCH * S_LEN * D_MODEL;
  const __hip_bfloat16* X = Xbf + (size_t)which * N;
  const __hip_bfloat16* W = Wt + (size_t)which * D_MODEL * D_MODEL;
  const float* bias = (which == 0) ? bq : (which == 1) ? bk : bv;
  const float bscale = (which == 0) ? ATTN_SCALE : 1.0f;

  // staging (2 x 16KB) and epilogue Cbuf (34KB) share the same LDS
  __shared__ __align__(16) char smem[128 * 136 * 2];
  __hip_bfloat16* Asm = (__hip_bfloat16*)smem;   // [128][64]
  __hip_bfloat16* Bsm = Asm + 128 * 64;          // [128][64]
  __hip_bfloat16* Cb  = (__hip_bfloat16*)smem;   // [128][136]

  const int tid  = threadIdx.x;
  const int lane = tid & 63;
  const int wv   = tid >> 6;
  const int lo16 = lane & 15;
  const int hi4  = lane >> 4;
  const int m0 = m_t * 128;
  const int n0 = n_t * 128;
  const int wm = (wv >> 1) * 64;
  const int wn = (wv & 1) * 64;

  f32x4 acc[4][4];
  const f32x4 z4 = {0.f, 0.f, 0.f, 0.f};
  for (int i = 0; i < 4; ++i)
    for (int j = 0; j < 4; ++j) acc[i][j] = z4;

  for (int k0 = 0; k0 < D_MODEL; k0 += 64) {
    __syncthreads();
    for (int it = 0; it < 4; ++it) {
      const int cbase = it * 256 + wv * 64;
      const int c = cbase + lane;
      const int row = c >> 3;
      const int kc = ((c & 7) ^ (row & 7)) * 8;   // inverse swizzle on source
      gld_lds16(X + (size_t)(m0 + row) * D_MODEL + k0 + kc, &Asm[cbase * 8]);
      gld_lds16(W + (size_t)(n0 + row) * D_MODEL + k0 + kc, &Bsm[cbase * 8]);
    }
    __syncthreads();

    for (int kk = 0; kk < 2; ++kk) {
      bf16x8 af[4], bfr[4];
      const int sl = (kk * 4 + hi4);
      for (int i = 0; i < 4; ++i) {
        const int lm = wm + 16 * i + lo16;
        af[i] = *(const bf16x8*)&Asm[lm * 64 + ((sl ^ (lm & 7)) * 8)];
      }
      for (int j = 0; j < 4; ++j) {
        const int ln = wn + 16 * j + lo16;
        bfr[j] = *(const bf16x8*)&Bsm[ln * 64 + ((sl ^ (ln & 7)) * 8)];
      }
      for (int i = 0; i < 4; ++i)
        for (int j = 0; j < 4; ++j)
          acc[i][j] = mfma16(af[i], bfr[j], acc[i][j]);
    }
  }

  // ---- epilogue: repack through LDS, then coalesced b128 stores ----
  const int b  = m0 >> 11;
  const int s0 = m0 & (S_LEN - 1);
  const int h  = n0 >> 7;                 // n-tile == one head
  const size_t bh = (size_t)(b * NH + h);

  __syncthreads();                        // protect last frag reads
  for (int j = 0; j < 4; ++j) {
    const int nl = wn + 16 * j + lo16;    // local d
    const float bval = bias[n0 + nl] * bscale;
    for (int i = 0; i < 4; ++i) {
      for (int r = 0; r < 4; ++r) {
        const int lm = wm + 16 * i + hi4 * 4 + r;   // local token row
        const __hip_bfloat16 ob = __float2bfloat16(acc[i][j][r] + bval);
        if (which == 2) {
          // transposed + slot-permuted: Cb[d][(lm&96) + slot]
          const int col = (lm & 96) + 2 * (lm & 15) + ((lm >> 4) & 1);
          Cb[nl * 136 + col] = ob;
        } else {
          Cb[lm * 136 + nl] = ob;
        }
      }
    }
  }
  __syncthreads();

  if (which == 0) {
    __hip_bfloat16* gq = Qo + (bh * S_LEN + s0) * DK;
    for (int r8 = 0; r8 < 8; ++r8) {
      const int C = r8 * 256 + tid;                  // 0..2047
      const bf16x8 v = *(const bf16x8*)&Cb[(C >> 4) * 136 + (C & 15) * 8];
      *(bf16x8*)&gq[(size_t)C * 8] = v;
    }
  } else if (which == 1) {
    __hip_bfloat16* gk = Ko + (bh * 64 + (s0 >> 5)) * 4096;
    for (int r8 = 0; r8 < 8; ++r8) {
      const int C = r8 * 256 + tid;
      const int su = C >> 9, Cw = C & 511;
      const bf16x8 v =
          *(const bf16x8*)&Cb[(su * 32 + (Cw & 31)) * 136 + (Cw >> 5) * 8];
      *(bf16x8*)&gk[(size_t)su * 4096 + (Cw >> 5) * 256 + (Cw & 31) * 8] = v;
    }
  } else {
    __hip_bfloat16* gv = Vo + (bh * 64 + (s0 >> 5)) * 4096;
    for (int r8 = 0; r8 < 8; ++r8) {
      const int C = r8 * 256 + tid;
      const int su = C >> 9, Cw = C & 511;
      const bf16x8 v =
          *(const bf16x8*)&Cb[(C & 127) * 136 + su * 32 + (Cw >> 7) * 8];
      *(bf16x8*)&gv[(size_t)su * 4096 + (size_t)Cw * 8] = v;
    }
  }
}

// ---------------------------------------------------------------------------
// Kernel 2: causal flash attention. R5: V NEVER TOUCHES LDS.
//
// R4 post-mortem: LDS pipe ~92% saturated (72KB frag reads + 16KB stage
// writes per CU per block-step vs 3170-cyc period). All 4 waves read
// IDENTICAL K/V fragments; the V duplication moves to L1/L2: the global
// tile-blocked V image is byte-identical to the old LDS image, so each
// wave global_load_dwordx4's its 8 V-frags directly to registers (L2-hot:
// the 4 waves touch the same 8KB tile within ~1us). LDS traffic/wave-step
// 18.25KB -> 10.25KB. V-loads issue BEFORE the K-stage gld_lds so the
// FIFO vmcnt for vf drains at vmcnt(2), leaving the K prefetch in flight.
// V-load latency hides under QK^T+softmax. LDS 43KB -> 26.6KB;
// launch_bounds(256,3) pins 3 waves/EU so 3 blocks/CU survives +32 VGPR.
// Schedule: 768 blocks = 256 CUs x 3 slots, balanced 68-step triples
// (ATTN_TBL); split-KV tiles 8..15 emit additive fp32 partials.
// ---------------------------------------------------------------------------
__device__ const uint32_t ATTN_TBL[24] = {
  // pack = tile | chunk<<4 | nchunks<<5 ; rows j=0..7, cols r=0..2
  79, 95, 32,   // t15h0(32) t15h1(32) t0(4)
  78, 94, 33,   // t14h0(30) t14h1(30) t1(8)
  77, 93, 34,   // t13h0(28) t13h1(28) t2(12)
  76, 92, 35,   // t12h0(26) t12h1(26) t3(16)
  75, 91, 36,   // t11h0(24) t11h1(24) t4(20)
  39, 72, 88,   // t7(32)    t8h0(18)  t8h1(18)
  38, 73, 89,   // t6(28)    t9h0(20)  t9h1(20)
  37, 74, 90    // t5(24)    t10h0(22) t10h1(22)
};

__global__ __launch_bounds__(256, 3) void attn_kernel(
    const __hip_bfloat16* __restrict__ Qw, const __hip_bfloat16* __restrict__ Kw,
    const __hip_bfloat16* __restrict__ Vtw, __hip_bfloat16* __restrict__ Og,
    float* __restrict__ partO, float* __restrict__ lsumP) {
  const int bid = blockIdx.x;       // 0..767
  const int q8  = bid & 255;        // CU slot-column; q8%8 = bh%8 = h (XCD pin)
  const int rr  = bid >> 8;         // dispatch round 0..2
  const int bh  = q8 & 31;
  const int jrow = q8 >> 5;         // 0..7
  const int h   = bh & 7;
  const int b   = bh >> 3;
  const uint32_t wi = ATTN_TBL[jrow * 3 + rr];
  const int  t     = wi & 15;
  const int  chnk  = (wi >> 4) & 1;
  const bool split = (wi >> 5) == 2;
  const int  half  = 2 * t + 2;
  const int  st0   = (split && chnk == 1) ? half : 0;
  const int  stN   = (split && chnk == 0) ? half : (4 * t + 4);

  const int tid  = threadIdx.x;
  const int lane = tid & 63;
  const int wv   = tid >> 6;
  const int lo16 = lane & 15;
  const int hi4  = lane >> 4;

  const int qrow0 = t * 128 + wv * 32;   // this wave's 32 q rows (global)
  const int ns_w  = 4 * t + wv + 1;      // causal kv32 limit for this wave

  const size_t bhp = (size_t)(b * NH + h);
  const __hip_bfloat16* Qp = Qw + bhp * S_LEN * DK;
  const __hip_bfloat16* Kp = Kw + bhp * S_LEN * DK;   // tile-blocked image
  const __hip_bfloat16* Vp = Vtw + bhp * S_LEN * DK;  // tile-blocked image

  __shared__ __align__(16) __hip_bfloat16 Ksm[2][32 * 128];  // [d16][kv32][8]
  __shared__ __align__(16) __hip_bfloat16 Psm[4][32 * 40];   // per-wave P (pairs)

  // Q fragments: A[m=lo16][k=hi4*8+j]; 2 m-groups x 4 k-steps cover 32q x 128d
  bf16x8 qf[2][4];
  for (int m = 0; m < 2; ++m)
    for (int kk = 0; kk < 4; ++kk)
      qf[m][kk] = *(const bf16x8*)&Qp[(size_t)(qrow0 + m * 16 + lo16) * DK +
                                      kk * 32 + hi4 * 8];

  f32x4 oacc[2][8];
  const f32x4 z4 = {0.f, 0.f, 0.f, 0.f};
  for (int m = 0; m < 2; ++m)
    for (int j = 0; j < 8; ++j) oacc[m][j] = z4;
  float lsum[2][4];
  for (int m = 0; m < 2; ++m)
    for (int i = 0; i < 4; ++i) lsum[m][i] = 0.f;

  // K staging: tile st is 8KB contiguous; lane c reads c*16B -> coalesced.
  const __hip_bfloat16* kbase[2];
#pragma unroll
  for (int it = 0; it < 2; ++it)
    kbase[it] = Kp + (size_t)(it * 256 + tid) * 8;
  auto stage = [&](int st, int buf) {
#pragma unroll
    for (int it = 0; it < 2; ++it) {
      const int cb = (it * 256 + wv * 64) * 8;
      gld_lds16(kbase[it] + ((size_t)st << 12), &Ksm[buf][cb]);
    }
  };

  stage(st0, 0);

  int bsel = 0;
  for (int st = st0; st < stN; ++st) {
    // K tile st's 2 loads were issued one full compute phase ago
    asm volatile("s_waitcnt vmcnt(0)" ::: "memory");
    __builtin_amdgcn_s_barrier();
    asm volatile("" ::: "memory");  // no LDS reads hoist above the barrier

    const bool act = st < ns_w;

    // V fragments straight from global (L2-hot tile); issued BEFORE the
    // next K-stage so vf's completion wait leaves the stage in flight.
    bf16x8 vf[8];
    if (act) {
      const __hip_bfloat16* vt = Vp + ((size_t)st << 12);
#pragma unroll
      for (int j = 0; j < 8; ++j)
        vf[j] = *(const bf16x8*)&vt[(hi4 * 128 + j * 16 + lo16) * 8];
    }
    // prefetch next K tile into the buffer everyone finished reading
    if (st + 1 < stN) stage(st + 1, bsel ^ 1);

    if (act) {
      const __hip_bfloat16* Kb = Ksm[bsel];

      // QK^T: S[32q][32kv] as 2m x 2kn 16x16 tiles
      bf16x8 kf[2][4];
      for (int kn = 0; kn < 2; ++kn)
        for (int kk = 0; kk < 4; ++kk)
          kf[kn][kk] = *(const bf16x8*)&Kb[((kk * 4 + hi4) * 32 + kn * 16 + lo16) * 8];
      f32x4 sc[2][2];
      for (int m = 0; m < 2; ++m)
        for (int kn = 0; kn < 2; ++kn) {
          f32x4 s4 = z4;
          for (int kk = 0; kk < 4; ++kk)
            s4 = mfma16(qf[m][kk], kf[kn][kk], s4);
          sc[m][kn] = s4;
        }

      // constant-max softmax; C/D row = hi4*4+reg, col = lo16.
      // P pair (kv=lo16, kv=16+lo16) packed into one b32 write at col 2*lo16
      // (kv-interleaved slot order, matching the V image).
      const int kv0 = st << 5;
      const bool do_mask = (st == ns_w - 1);  // only the diagonal step masks
      for (int m = 0; m < 2; ++m) {
        for (int i = 0; i < 4; ++i) {
          const int qg = qrow0 + m * 16 + hi4 * 4 + i;
          float s0 = sc[m][0][i];
          float s1 = sc[m][1][i];
          if (do_mask) {
            if (kv0 + lo16 > qg)      s0 = -1.0e30f;
            if (kv0 + 16 + lo16 > qg) s1 = -1.0e30f;
          }
          const float p0 = __expf(s0 - 8.f);
          const float p1 = __expf(s1 - 8.f);
          lsum[m][i] += p0 + p1;
          const int prw = m * 16 + hi4 * 4 + i;
          *(__hip_bfloat162*)&Psm[wv][prw * 40 + 2 * lo16] =
              __float22bfloat162_rn(make_float2(p0, p1));
        }
      }
      // wave-local LDS round-trip: order + drain without any barrier
      asm volatile("s_waitcnt lgkmcnt(0)" ::: "memory");

      // PV: A = P[q16][slot32] per m-group, B = V[d][slot] in registers
      bf16x8 pf[2];
      for (int m = 0; m < 2; ++m)
        pf[m] = *(const bf16x8*)&Psm[wv][(m * 16 + lo16) * 40 + hi4 * 8];
      for (int j = 0; j < 8; ++j) {
        oacc[0][j] = mfma16(pf[0], vf[j], oacc[0][j]);
        oacc[1][j] = mfma16(pf[1], vf[j], oacc[1][j]);
      }
    }
    bsel ^= 1;
  }

  // epilogue: row-sum reduce over 16-lane groups, then either normalized
  // bf16 O (whole-tile blocks) or fp32 partials (split-tile blocks).
  for (int m = 0; m < 2; ++m) {
    for (int i = 0; i < 4; ++i) {
      float l = lsum[m][i];
      l += __shfl_xor(l, 1);
      l += __shfl_xor(l, 2);
      l += __shfl_xor(l, 4);
      l += __shfl_xor(l, 8);
      const int row = wv * 32 + m * 16 + hi4 * 4 + i;   // row within tile
      if (!split) {
        const float inv = 1.0f / l;
        const int qg = t * 128 + row;
        __hip_bfloat16* orow = Og + ((size_t)b * S_LEN + qg) * D_MODEL + h * DK;
        for (int j = 0; j < 8; ++j)
          orow[j * 16 + lo16] = __float2bfloat16(oacc[m][j][i] * inv);
      } else {
        const int pidx = bh * 8 + (t - 8);               // 0..255
        float* prow = partO +
            (((size_t)chnk * 256 + pidx) * 128 + row) * 128;
        for (int j = 0; j < 8; ++j)
          prow[j * 16 + lo16] = oacc[m][j][i];
        if (lo16 == 0)
          lsumP[(chnk * 256 + pidx) * 128 + row] = l;
      }
    }
  }
}

// ---------------------------------------------------------------------------
// Kernel 3: residual + LayerNorm, one block per row. Rows in tiles 8..15
// additionally combine the two split-KV partials: (p0+p1)/(l0+l1).
// ---------------------------------------------------------------------------
__global__ __launch_bounds__(256) void ln_kernel(
    const __hip_bfloat16* __restrict__ Og, const float* __restrict__ partO,
    const float* __restrict__ lsumP, const float* __restrict__ resid_in,
    const float* __restrict__ gamma, const float* __restrict__ beta,
    float* __restrict__ out) {
  const int row  = blockIdx.x;          // 0..8191
  const int b    = row >> 11;
  const int srow = row & (S_LEN - 1);
  const int tile = srow >> 7;
  const int tid  = threadIdx.x;
  const int base = tid * 4;
  const float4 q4 = *(const float4*)(resid_in + (size_t)row * D_MODEL + base);
  float v[4];
  if (tile < 8) {
    const __hip_bfloat16* orow = Og + (size_t)row * D_MODEL;
    const ushort4 o4 = *(const ushort4*)(orow + base);
    v[0] = __bfloat162float(*(const __hip_bfloat16*)&o4.x) + q4.x;
    v[1] = __bfloat162float(*(const __hip_bfloat16*)&o4.y) + q4.y;
    v[2] = __bfloat162float(*(const __hip_bfloat16*)&o4.z) + q4.z;
    v[3] = __bfloat162float(*(const __hip_bfloat16*)&o4.w) + q4.w;
  } else {
    const int h    = base >> 7;
    const int rin  = srow & 127;
    const int pidx = (b * 8 + h) * 8 + (tile - 8);
    const size_t off = ((size_t)pidx * 128 + rin) * 128 + (base & 127);
    const float4 p0 = *(const float4*)(partO + off);
    const float4 p1 = *(const float4*)(partO + (size_t)256 * 128 * 128 + off);
    const float l = lsumP[pidx * 128 + rin] +
                    lsumP[256 * 128 + pidx * 128 + rin];
    const float inv = 1.0f / l;
    v[0] = (p0.x + p1.x) * inv + q4.x;
    v[1] = (p0.y + p1.y) * inv + q4.y;
    v[2] = (p0.z + p1.z) * inv + q4.z;
    v[3] = (p0.w + p1.w) * inv + q4.w;
  }
  float s = v[0] + v[1] + v[2] + v[3];
  float ss = v[0] * v[0] + v[1] * v[1] + v[2] * v[2] + v[3] * v[3];
  for (int m = 1; m < 64; m <<= 1) { s += __shfl_xor(s, m); ss += __shfl_xor(ss, m); }
  __shared__ float red[8];
  const int wv = tid >> 6, lane = tid & 63;
  if (lane == 0) { red[wv] = s; red[4 + wv] = ss; }
  __syncthreads();
  s  = red[0] + red[1] + red[2] + red[3];
  ss = red[4] + red[5] + red[6] + red[7];
  const float mu  = s * (1.0f / D_MODEL);
  const float var = ss * (1.0f / D_MODEL) - mu * mu;
  const float rstd = rsqrtf(var + 1e-6f);
  const float4 g4 = *(const float4*)(gamma + base);
  const float4 b4 = *(const float4*)(beta + base);
  float4 o;
  o.x = (v[0] - mu) * rstd * g4.x + b4.x;
  o.y = (v[1] - mu) * rstd * g4.y + b4.y;
  o.z = (v[2] - mu) * rstd * g4.z + b4.z;
  o.w = (v[3] - mu) * rstd * g4.w + b4.w;
  *(float4*)(out + (size_t)row * D_MODEL + base) = o;
}

// ---------------------------------------------------------------------------
extern "C" void kernel_launch(void* const* d_in, const int* in_sizes, int n_in,
                              void* d_out, int out_size, void* d_ws, size_t ws_size,
                              hipStream_t stream) {
  const float* queries = (const float*)d_in[0];
  const float* keys    = (const float*)d_in[1];
  const float* values  = (const float*)d_in[2];
  const float* Wq = (const float*)d_in[3];
  const float* bq = (const float*)d_in[4];
  const float* Wk = (const float*)d_in[5];
  const float* bk = (const float*)d_in[6];
  const float* Wv = (const float*)d_in[7];
  const float* bv = (const float*)d_in[8];
  const float* gamma = (const float*)d_in[9];
  const float* beta  = (const float*)d_in[10];

  char* ws = (char*)d_ws;
  const size_t N = (size_t)BATCH * S_LEN * D_MODEL;                 // 8M
  const size_t WT_BYTES  = (size_t)3 * D_MODEL * D_MODEL * 2;      // 6 MB
  const size_t XBF_BYTES = (size_t)3 * N * 2;                      // 48 MB
  const size_t QKV_BYTES = (size_t)BATCH * NH * S_LEN * DK * 2;    // 16 MB
  const size_t OG_BYTES  = (size_t)BATCH * S_LEN * D_MODEL * 2;    // 16 MB
  __hip_bfloat16* Wt  = (__hip_bfloat16*)ws;
  __hip_bfloat16* Xbf = (__hip_bfloat16*)(ws + WT_BYTES);
  // After qkv_gemm, the Xbf (48MB) and Wt (6MB) regions are dead:
  //   Og   bf16 16MB  @ XBF+0      (rows of tiles 0..7 only)
  //   partO f32 32MB  @ XBF+16MB   ([2 splits][256 pidx][128 row][128 d])
  //   lsumP f32 256KB @ ws+0       ([2 splits][256 pidx][128 row])
  __hip_bfloat16* Ogs = (__hip_bfloat16*)(ws + WT_BYTES);
  float* partO = (float*)(ws + WT_BYTES + OG_BYTES);
  float* lsumP = (float*)ws;
  __hip_bfloat16* Qws = (__hip_bfloat16*)(ws + WT_BYTES + XBF_BYTES);
  __hip_bfloat16* Kws = (__hip_bfloat16*)(ws + WT_BYTES + XBF_BYTES + QKV_BYTES);
  __hip_bfloat16* Vws = (__hip_bfloat16*)(ws + WT_BYTES + XBF_BYTES + 2 * QKV_BYTES);

  cvt_kernel<<<dim3((unsigned)(N / 1024), 3), 256, 0, stream>>>(queries, keys, values, Xbf);
  wtrans_kernel<<<dim3(32, 32, 3), dim3(32, 8), 0, stream>>>(Wq, Wk, Wv, Wt);
  qkv_gemm_kernel<<<dim3(1536), 256, 0, stream>>>(
      Xbf, bq, bk, bv, Wt, Qws, Kws, Vws);
  attn_kernel<<<dim3(768), 256, 0, stream>>>(Qws, Kws, Vws, Ogs, partO, lsumP);
  ln_kernel<<<dim3(BATCH * S_LEN), 256, 0, stream>>>(Ogs, partO, lsumP, queries,
                                                     gamma, beta, (float*)d_out);
}